// Round 13
// baseline (2130.295 us; speedup 1.0000x reference)
//
#include <hip/hip_runtime.h>
#include <hip/hip_bf16.h>

#define N_NODES   32768
#define N_EDGES   65536
#define NGRAPH    512
#define DIM       64
#define NFEAT     14
#define NHID      128
#define WCOLS     4096
#define NSTEM     1024
#define NOUT      105

typedef __attribute__((ext_vector_type(8))) short short8;
typedef __attribute__((ext_vector_type(4))) float f32x4;

__device__ __forceinline__ float bf2f(unsigned int u16) {
  union { unsigned int i; float f; } c; c.i = u16 << 16; return c.f;
}
__device__ __forceinline__ unsigned short f2bf(float f) {
  union { float f; unsigned int i; } c; c.f = f;
  return (unsigned short)((c.i + 0x7fffu + ((c.i >> 16) & 1u)) >> 16);
}
__device__ __forceinline__ float leaky(float x) { return x > 0.f ? x : 0.01f * x; }
__device__ __forceinline__ float sigm(float x) { return 1.f / (1.f + expf(-x)); }

constexpr size_t ALN(size_t x) { return (x + 255) & ~(size_t)255; }

// ---------------- fixed workspace layout (~55 MB) ----------------
constexpr size_t OFF_HIDP = 0;
constexpr size_t SZ_HIDP  = (size_t)N_EDGES * NHID * 2;       // 16 MB bf16 (CSR order)
constexpr size_t OFF_T2T  = ALN(OFF_HIDP + SZ_HIDP);
constexpr size_t SZ_T2T   = (size_t)WCOLS * NHID * 2;         // 1 MB
constexpr size_t OFF_B2T  = ALN(OFF_T2T + SZ_T2T);
constexpr size_t SZ_B2T   = (size_t)WCOLS * 4;
constexpr size_t OFF_STATE= ALN(OFF_B2T + SZ_B2T);
constexpr size_t SZ_STATE = (size_t)N_NODES * DIM * 4;        // 8 MB
constexpr size_t OFF_AGG  = ALN(OFF_STATE + SZ_STATE);
constexpr size_t SZ_AGG   = SZ_STATE;                         // 8 MB
constexpr size_t OFF_IDEG = ALN(OFF_AGG + SZ_AGG);
constexpr size_t SZ_IDEG  = (size_t)N_NODES * 4;
constexpr size_t OFF_CNT  = ALN(OFF_IDEG + SZ_IDEG);
constexpr size_t SZ_CNT   = (size_t)N_NODES * 4;
constexpr size_t OFF_RP   = ALN(OFF_CNT + SZ_CNT);
constexpr size_t SZ_RP    = (size_t)(N_NODES + 1) * 4;
constexpr size_t OFF_CUR  = ALN(OFF_RP + SZ_RP);
constexpr size_t SZ_CUR   = (size_t)N_NODES * 4;
constexpr size_t OFF_SRCP = ALN(OFF_CUR + SZ_CUR);
constexpr size_t SZ_SRCP  = (size_t)N_EDGES * 4;
constexpr size_t OFF_DSTP = ALN(OFF_SRCP + SZ_SRCP);
constexpr size_t SZ_DSTP  = (size_t)N_EDGES * 4;
constexpr size_t OFF_EPOS = ALN(OFF_DSTP + SZ_DSTP);
constexpr size_t SZ_EPOS  = (size_t)N_EDGES * 4;
constexpr size_t OFF_BW1  = ALN(OFF_EPOS + SZ_EPOS);
constexpr size_t SZ_BW1   = 32 * 64 * 8 * 2;                  // frag-major: 32 frags
constexpr size_t OFF_BW2  = ALN(OFF_BW1 + SZ_BW1);
constexpr size_t SZ_BW2   = 24 * 64 * 8 * 2;                  // 24 frags
constexpr size_t OFF_WIH  = ALN(OFF_BW2 + SZ_BW2);
constexpr size_t SZ_WIH   = 128 * 256 * 4;
constexpr size_t OFF_WHH  = ALN(OFF_WIH + SZ_WIH);
constexpr size_t SZ_WHH   = 64 * 256 * 4;
constexpr size_t OFF_S8   = ALN(OFF_WHH + SZ_WHH);
constexpr size_t SZ_S8    = (size_t)N_NODES * 64;             // 2 MB int8 state
constexpr size_t OFF_SSC  = ALN(OFF_S8 + SZ_S8);
constexpr size_t SZ_SSC   = (size_t)N_NODES * 4;
constexpr size_t OFF_SCL  = ALN(OFF_SSC + SZ_SSC);
constexpr size_t SZ_SCL   = (size_t)N_EDGES * 64 * 4;         // 16 MB
constexpr size_t OFF_WT   = ALN(OFF_SCL + SZ_SCL);            // W8 base

// ---------------- prep kernels ----------------
__global__ void k_deg(const int* __restrict__ dst, int* __restrict__ cnt) {
  int e = blockIdx.x * 256 + threadIdx.x;
  atomicAdd(&cnt[dst[e]], 1);
}
__global__ __launch_bounds__(1024) void k_scan(const int* __restrict__ cnt,
                                               int* __restrict__ rp,
                                               int* __restrict__ cur,
                                               float* __restrict__ ideg) {
  __shared__ int part[1024];
  const int t = threadIdx.x, base = t * 32;
  int s = 0;
  for (int i = 0; i < 32; ++i) s += cnt[base + i];
  part[t] = s;
  __syncthreads();
  for (int off = 1; off < 1024; off <<= 1) {
    int v = (t >= off) ? part[t - off] : 0;
    __syncthreads();
    part[t] += v;
    __syncthreads();
  }
  int run = part[t] - s;
  for (int i = 0; i < 32; ++i) {
    int c = cnt[base + i];
    rp[base + i] = run; cur[base + i] = run;
    ideg[base + i] = 1.0f / fmaxf((float)c, 1.0f);
    run += c;
  }
  if (t == 1023) rp[N_NODES] = run;
}
__global__ void k_permute(const int* __restrict__ src, const int* __restrict__ dst,
                          int* __restrict__ cur, int* __restrict__ src_p,
                          int* __restrict__ dst_p, int* __restrict__ epos) {
  int e = blockIdx.x * 256 + threadIdx.x;
  int d = dst[e];
  int p = atomicAdd(&cur[d], 1);
  src_p[p] = src[e]; dst_p[p] = d; epos[e] = p;
}
// T2t[r=o*64+i][h] = net_w2[(i*64+o)][h]; b2t[r] = net_b2[i*64+o]
__global__ void k_prep_t2(const float* __restrict__ w2, const float* __restrict__ b2,
                          unsigned short* __restrict__ T2t, float* __restrict__ b2t) {
  int gid = blockIdx.x * 256 + threadIdx.x;
  int r = gid >> 7, h = gid & 127;
  int srow = (r & 63) * 64 + (r >> 6);
  T2t[gid] = f2bf(w2[(size_t)srow * 128 + h]);
  if (h == 0) b2t[r] = b2[srow];
}
// fragment-major gate weights: frag(nt,ks), lane ln=r+16g holds B[nt*16+r][ks*32+g*8+m]
__global__ void k_prep_gru(const float* __restrict__ root, const float* __restrict__ whh,
                           const float* __restrict__ wih,
                           unsigned short* __restrict__ BW1f, unsigned short* __restrict__ BW2f) {
  int gid = blockIdx.x * 256 + threadIdx.x;
  if (gid >= 64 * 448) return;
  int k = gid / 448, n = gid % 448;
  float v;
  if (n < 64)        v = root[k * 64 + n];          // B1 row n = conv_root^T
  else if (n < 256)  v = whh[(n - 64) * 64 + k];
  else               v = wih[(n - 256) * 64 + k];
  int ks = k >> 5, g = (k >> 3) & 3, m = k & 7;
  if (n < 256) {
    int nt = n >> 4, r = n & 15, ln = r + 16 * g;
    BW1f[(((nt * 2 + ks) * 64 + ln) << 3) + m] = f2bf(v);
  } else {
    int n2 = n - 256, nt = n2 >> 4, r = n2 & 15, ln = r + 16 * g;
    BW2f[(((nt * 2 + ks) * 64 + ln) << 3) + m] = f2bf(v);
  }
}
__global__ void k_prep_s2s(const float* __restrict__ wih, const float* __restrict__ whh,
                           float* __restrict__ wihT, float* __restrict__ whhT) {
  int gid = blockIdx.x * 256 + threadIdx.x;
  if (gid < 32768) { int j = gid >> 8, k = gid & 255; wihT[gid] = wih[k * 128 + j]; }
  else { int g2 = gid - 32768; int j = g2 >> 8, k = g2 & 255; whhT[g2] = whh[k * 64 + j]; }
}
__global__ void k_lin0(const float* __restrict__ x, const float* __restrict__ w,
                       const float* __restrict__ b, float* __restrict__ state) {
  int gid = blockIdx.x * 256 + threadIdx.x;
  int n = gid >> 6, o = gid & 63;
  float acc = b[o];
  #pragma unroll
  for (int f = 0; f < NFEAT; ++f) acc += x[(size_t)n * NFEAT + f] * w[o * NFEAT + f];
  state[gid] = leaky(acc);
}
__global__ void k_hidden(const float* __restrict__ ea, const float* __restrict__ w1,
                         const float* __restrict__ b1, const int* __restrict__ epos,
                         unsigned short* __restrict__ hid_p) {
  int gid = blockIdx.x * 256 + threadIdx.x;
  int e = gid >> 7, h = gid & 127;
  float acc = b1[h];
  #pragma unroll
  for (int d = 0; d < 4; ++d) acc += ea[(size_t)e * 4 + d] * w1[h * 4 + d];
  hid_p[(size_t)epos[e] * 128 + h] = f2bf(leaky(acc));
}
// quantize state rows to int8 (wave per node)
__global__ __launch_bounds__(256) void k_qstate(const float* __restrict__ state,
                                                char* __restrict__ s8,
                                                float* __restrict__ sscale) {
  __shared__ char q8[4][64];
  __shared__ float scs[4];
  const int t = threadIdx.x, wv = t >> 6, ln = t & 63;
  const int n = blockIdx.x * 4 + wv;
  float v = state[(size_t)n * 64 + ln];
  float m = fabsf(v);
  #pragma unroll
  for (int off = 1; off < 64; off <<= 1) m = fmaxf(m, __shfl_xor(m, off));
  float inv = m > 0.f ? 127.f / m : 0.f;
  q8[wv][ln] = (char)(int)rintf(v * inv);
  if (ln == 0) scs[wv] = m * (1.f / 127.f);
  __syncthreads();
  if (t < 64) {
    int w2 = t >> 4, c = t & 15;
    reinterpret_cast<int*>(s8)[((size_t)(blockIdx.x * 4 + w2)) * 16 + c] =
        reinterpret_cast<const int*>(q8[w2])[c];
  }
  if (t < 4) sscale[blockIdx.x * 4 + t] = scs[t];
}

// ---------------- W build GEMM: int8 output, chunk-coalesced layout (r9) ----------------
// W8[e*4096 + (i>>4)*1024 + o*16 + (i&15)] ; SCL[e*64 + o]
#define WG_PAD 136
__global__ __launch_bounds__(256) void k_wgemm(const unsigned short* __restrict__ A,
                                               const unsigned short* __restrict__ Bt,
                                               const float* __restrict__ b2t,
                                               unsigned char* __restrict__ W8,
                                               float* __restrict__ SCL) {
  __shared__ __align__(16) unsigned short As[64 * WG_PAD];
  __shared__ __align__(16) unsigned short Bs[64 * WG_PAD];
  __shared__ __align__(16) char pk[64][64];
  const int nb = blockIdx.x, mb = blockIdx.y, t = threadIdx.x;
  #pragma unroll
  for (int j = 0; j < 4; ++j) {
    int c = t + 256 * j;
    int row = c >> 4, col8 = (c & 15) * 8;
    *reinterpret_cast<uint4*>(&As[row * WG_PAD + col8]) =
        *reinterpret_cast<const uint4*>(A + (size_t)(mb * 64 + row) * 128 + col8);
    *reinterpret_cast<uint4*>(&Bs[row * WG_PAD + col8]) =
        *reinterpret_cast<const uint4*>(Bt + (size_t)(nb * 64 + row) * 128 + col8);
  }
  __syncthreads();
  const int wv = t >> 6, ln = t & 63, r = ln & 15, g = ln >> 4;
  f32x4 acc[4] = {};
  #pragma unroll
  for (int ks = 0; ks < 4; ++ks) {
    int kk = ks * 32 + g * 8;
    short8 a = *reinterpret_cast<const short8*>(&As[(wv * 16 + r) * WG_PAD + kk]);
    #pragma unroll
    for (int nt = 0; nt < 4; ++nt) {
      short8 b = *reinterpret_cast<const short8*>(&Bs[(nt * 16 + r) * WG_PAD + kk]);
      acc[nt] = __builtin_amdgcn_mfma_f32_16x16x32_bf16(a, b, acc[nt], 0, 0, 0);
    }
  }
  float bias[4];
  #pragma unroll
  for (int nt = 0; nt < 4; ++nt) bias[nt] = b2t[nb * 64 + nt * 16 + r];
  #pragma unroll
  for (int j = 0; j < 4; ++j) {
    int e_l = wv * 16 + g * 4 + j;
    float w[4], m = 0.f;
    #pragma unroll
    for (int nt = 0; nt < 4; ++nt) { w[nt] = acc[nt][j] + bias[nt]; m = fmaxf(m, fabsf(w[nt])); }
    m = fmaxf(m, __shfl_xor(m, 1)); m = fmaxf(m, __shfl_xor(m, 2));
    m = fmaxf(m, __shfl_xor(m, 4)); m = fmaxf(m, __shfl_xor(m, 8));
    float inv = m > 0.f ? 127.f / m : 0.f;
    #pragma unroll
    for (int nt = 0; nt < 4; ++nt)
      pk[e_l][nt * 16 + r] = (char)(int)rintf(w[nt] * inv);
    if (r == 0) {
      size_t e8 = (size_t)mb * 64 + e_l;
      SCL[e8 * 64 + nb] = m * (1.f / 127.f);
    }
  }
  __syncthreads();
  {
    int e_l = t >> 2, jc = t & 3;
    size_t e8 = (size_t)mb * 64 + e_l;
    *reinterpret_cast<uint4*>(W8 + e8 * 4096 + jc * 1024 + nb * 16) =
        *reinterpret_cast<const uint4*>(&pk[e_l][jc * 16]);
  }
}

// ---------------- per-step msg: CSR gather, int8 x int8 via sdot4 (r9) ----------------
__device__ __forceinline__ int dot64(const uint4* __restrict__ wp, const int* __restrict__ s) {
  int u = 0;
  #pragma unroll
  for (int j = 0; j < 4; ++j) {
    uint4 v = wp[j * 64];                       // +j*1024 bytes
    u = __builtin_amdgcn_sdot4((int)v.x, s[j * 4 + 0], u, false);
    u = __builtin_amdgcn_sdot4((int)v.y, s[j * 4 + 1], u, false);
    u = __builtin_amdgcn_sdot4((int)v.z, s[j * 4 + 2], u, false);
    u = __builtin_amdgcn_sdot4((int)v.w, s[j * 4 + 3], u, false);
  }
  return u;
}

__global__ __launch_bounds__(256) void k_msg_csr(const unsigned char* __restrict__ W8,
                                                 const float* __restrict__ SCL,
                                                 const char* __restrict__ s8,
                                                 const float* __restrict__ sscale,
                                                 int lim8,
                                                 const int* __restrict__ rp,
                                                 const int* __restrict__ src_p,
                                                 const float* __restrict__ ideg,
                                                 float* __restrict__ agg) {
  const int wv = threadIdx.x >> 6, ln = threadIdx.x & 63;
  const int d = blockIdx.x * 4 + wv;
  int k0 = rp[d], k1 = rp[d + 1];
  if (k1 > lim8) k1 = lim8;            // tail edges handled by k_wmsg
  float acc = 0.f;
  int k = k0;
  for (; k + 2 <= k1; k += 2) {
    const uint4* wA = reinterpret_cast<const uint4*>(W8 + (size_t)k * 4096 + ln * 16);
    const uint4* wB = reinterpret_cast<const uint4*>(W8 + (size_t)(k + 1) * 4096 + ln * 16);
    int sA = __builtin_amdgcn_readfirstlane(src_p[k]);
    int sB = __builtin_amdgcn_readfirstlane(src_p[k + 1]);
    const int* rA = reinterpret_cast<const int*>(s8 + (size_t)sA * 64);
    const int* rB = reinterpret_cast<const int*>(s8 + (size_t)sB * 64);
    float fA = SCL[(size_t)k * 64 + ln] * sscale[sA];
    float fB = SCL[(size_t)k * 64 + 64 + ln] * sscale[sB];
    int uA = dot64(wA, rA);
    int uB = dot64(wB, rB);
    acc = fmaf((float)uA, fA, acc);
    acc = fmaf((float)uB, fB, acc);
  }
  if (k < k1) {
    const uint4* wA = reinterpret_cast<const uint4*>(W8 + (size_t)k * 4096 + ln * 16);
    int sA = __builtin_amdgcn_readfirstlane(src_p[k]);
    const int* rA = reinterpret_cast<const int*>(s8 + (size_t)sA * 64);
    float fA = SCL[(size_t)k * 64 + ln] * sscale[sA];
    acc = fmaf((float)dot64(wA, rA), fA, acc);
  }
  agg[(size_t)d * 64 + ln] = acc * ideg[d];
}

// ---------------- fallback transient (only if ws too small): adds on top ----------------
#define WM_PAD 136
__global__ __launch_bounds__(256) void k_wmsg(const unsigned short* __restrict__ hid,
                                              const unsigned short* __restrict__ T2t,
                                              const float* __restrict__ b2t,
                                              const float* __restrict__ state,
                                              const int* __restrict__ srcs,
                                              const int* __restrict__ dsts,
                                              const float* __restrict__ ideg,
                                              int e0,
                                              float* __restrict__ agg) {
  __shared__ __align__(16) unsigned short As[64 * WM_PAD];
  __shared__ __align__(16) unsigned short Bs[2][64 * WM_PAD];
  __shared__ __align__(16) float Ss[64][68];
  __shared__ int dstl[64]; __shared__ float idgl[64];
  __shared__ int srcl[64];
  const int t = threadIdx.x;
  const int eb = blockIdx.x * 64;
  if (t < 64) {
    int e = e0 + eb + t;
    srcl[t] = srcs[e];
    int d = dsts[e]; dstl[t] = d; idgl[t] = ideg[d];
  }
  __syncthreads();
  #pragma unroll
  for (int j = 0; j < 4; ++j) {
    int c = t + 256 * j;
    int row = c >> 4, col8 = (c & 15) * 8;
    *reinterpret_cast<uint4*>(&As[row * WM_PAD + col8]) =
        *reinterpret_cast<const uint4*>(hid + (size_t)(eb + row) * 128 + col8);
  }
  #pragma unroll
  for (int j = 0; j < 4; ++j) {
    int c = t + 256 * j;
    int row = c >> 4, q = (c & 15) * 4;
    *reinterpret_cast<float4*>(&Ss[row][q]) =
        *reinterpret_cast<const float4*>(state + (size_t)srcl[row] * 64 + q);
  }
  #pragma unroll
  for (int j = 0; j < 4; ++j) {
    int c = t + 256 * j;
    int row = c >> 4, col8 = (c & 15) * 8;
    *reinterpret_cast<uint4*>(&Bs[0][row * WM_PAD + col8]) =
        *reinterpret_cast<const uint4*>(T2t + (size_t)row * 128 + col8);
  }
  __syncthreads();
  const int wv = t >> 6, ln = t & 63, r = ln & 15, g = ln >> 4;
  for (int nb = 0; nb < 64; ++nb) {
    const int cur = nb & 1;
    if (nb + 1 < 64) {
      #pragma unroll
      for (int j = 0; j < 4; ++j) {
        int c = t + 256 * j;
        int row = c >> 4, col8 = (c & 15) * 8;
        *reinterpret_cast<uint4*>(&Bs[cur ^ 1][row * WM_PAD + col8]) =
            *reinterpret_cast<const uint4*>(T2t + (size_t)((nb + 1) * 64 + row) * 128 + col8);
      }
    }
    f32x4 acc[4] = {};
    #pragma unroll
    for (int ks = 0; ks < 4; ++ks) {
      int kk = ks * 32 + g * 8;
      short8 a = *reinterpret_cast<const short8*>(&As[(wv * 16 + r) * WM_PAD + kk]);
      #pragma unroll
      for (int nt = 0; nt < 4; ++nt) {
        short8 b = *reinterpret_cast<const short8*>(&Bs[cur][(nt * 16 + r) * WM_PAD + kk]);
        acc[nt] = __builtin_amdgcn_mfma_f32_16x16x32_bf16(a, b, acc[nt], 0, 0, 0);
      }
    }
    float bias[4];
    #pragma unroll
    for (int nt = 0; nt < 4; ++nt) bias[nt] = b2t[nb * 64 + nt * 16 + r];
    float pj[4];
    #pragma unroll
    for (int j = 0; j < 4; ++j) {
      int row = wv * 16 + g * 4 + j;
      float p = 0.f;
      #pragma unroll
      for (int nt = 0; nt < 4; ++nt)
        p += (acc[nt][j] + bias[nt]) * Ss[row][nt * 16 + r];
      pj[j] = p;
    }
    #pragma unroll
    for (int j = 0; j < 4; ++j) {
      float p = pj[j];
      p += __shfl_xor(p, 1); p += __shfl_xor(p, 2);
      p += __shfl_xor(p, 4); p += __shfl_xor(p, 8);
      pj[j] = p;
    }
    if (r == 0) {
      #pragma unroll
      for (int j = 0; j < 4; ++j) {
        int row = wv * 16 + g * 4 + j;
        atomicAdd(&agg[(size_t)dstl[row] * 64 + nb], pj[j] * idgl[row]);
      }
    }
    __syncthreads();
  }
}

// ---------------- per-step fused GRU: 64 rows/block, B-frags from global (L2) ------------
#define KPAD 72
__global__ __launch_bounds__(256) void k_gru(const float* __restrict__ agg,
                                             float* __restrict__ state,
                                             const unsigned short* __restrict__ BW1f,
                                             const unsigned short* __restrict__ BW2f,
                                             const float* __restrict__ conv_bias,
                                             const float* __restrict__ b_ih,
                                             const float* __restrict__ b_hh,
                                             char* __restrict__ s8,
                                             float* __restrict__ sscale) {
  __shared__ __align__(16) unsigned short As[64 * KPAD];   // 9.2 KB
  __shared__ __align__(16) unsigned short Ms[64 * KPAD];   // 9.2 KB
  const int t = threadIdx.x;
  const int rowbase = blockIdx.x * 64;
  #pragma unroll
  for (int j = 0; j < 2; ++j) {          // stage 64 state rows as bf16
    int c = t + 256 * j;
    int row = c >> 3, col8 = (c & 7) * 8;
    const float* sp = state + (size_t)(rowbase + row) * 64 + col8;
    float4 f0 = *reinterpret_cast<const float4*>(sp);
    float4 f1 = *reinterpret_cast<const float4*>(sp + 4);
    short8 hv;
    hv[0] = (short)f2bf(f0.x); hv[1] = (short)f2bf(f0.y);
    hv[2] = (short)f2bf(f0.z); hv[3] = (short)f2bf(f0.w);
    hv[4] = (short)f2bf(f1.x); hv[5] = (short)f2bf(f1.y);
    hv[6] = (short)f2bf(f1.z); hv[7] = (short)f2bf(f1.w);
    *reinterpret_cast<short8*>(&As[row * KPAD + col8]) = hv;
  }
  __syncthreads();
  const int wv = t >> 6, ln = t & 63, r = ln & 15, g = ln >> 4;
  // phase 1: C1 = h @ [conv_root | w_hh^T], B-frags streamed from global (L2-hot)
  f32x4 acc1[16] = {};
  #pragma unroll
  for (int ks = 0; ks < 2; ++ks) {
    int kk = ks * 32 + g * 8;
    short8 a = *reinterpret_cast<const short8*>(&As[(wv * 16 + r) * KPAD + kk]);
    #pragma unroll
    for (int nt = 0; nt < 16; ++nt) {
      short8 b = *reinterpret_cast<const short8*>(
          BW1f + (((nt * 2 + ks) * 64 + ln) << 3));
      acc1[nt] = __builtin_amdgcn_mfma_f32_16x16x32_bf16(a, b, acc1[nt], 0, 0, 0);
    }
  }
  // m = leaky(agg + R + conv_bias) -> Ms (bf16)
  #pragma unroll
  for (int nt = 0; nt < 4; ++nt) {
    int col = nt * 16 + r;
    float cb = conv_bias[col];
    #pragma unroll
    for (int j = 0; j < 4; ++j) {
      int lrow = wv * 16 + g * 4 + j;
      float mv = agg[(size_t)(rowbase + lrow) * 64 + col] + acc1[nt][j] + cb;
      Ms[lrow * KPAD + col] = f2bf(leaky(mv));
    }
  }
  __syncthreads();
  // phase 2: GI = m @ w_ih^T
  f32x4 acc2[12] = {};
  #pragma unroll
  for (int ks = 0; ks < 2; ++ks) {
    int kk = ks * 32 + g * 8;
    short8 a = *reinterpret_cast<const short8*>(&Ms[(wv * 16 + r) * KPAD + kk]);
    #pragma unroll
    for (int nt = 0; nt < 12; ++nt) {
      short8 b = *reinterpret_cast<const short8*>(
          BW2f + (((nt * 2 + ks) * 64 + ln) << 3));
      acc2[nt] = __builtin_amdgcn_mfma_f32_16x16x32_bf16(a, b, acc2[nt], 0, 0, 0);
    }
  }
  // gates (torch order r,z,n)
  float hnew[4][4];
  #pragma unroll
  for (int nt = 0; nt < 4; ++nt) {
    int o = nt * 16 + r;
    float bir = b_ih[o],       bhr = b_hh[o];
    float biz = b_ih[64 + o],  bhz = b_hh[64 + o];
    float bin = b_ih[128 + o], bhn = b_hh[128 + o];
    #pragma unroll
    for (int j = 0; j < 4; ++j) {
      size_t gidx = (size_t)(rowbase + wv * 16 + g * 4 + j) * 64 + o;
      float rr = sigm(acc2[nt][j] + bir + acc1[4 + nt][j] + bhr);
      float zz = sigm(acc2[4 + nt][j] + biz + acc1[8 + nt][j] + bhz);
      float nn = tanhf(acc2[8 + nt][j] + bin + rr * (acc1[12 + nt][j] + bhn));
      float hold = state[gidx];
      float hv = (1.f - zz) * nn + zz * hold;
      state[gidx] = hv;
      hnew[nt][j] = hv;
    }
  }
  // re-quantize new state rows to int8 (As reused as byte tile — dead after phase 1)
  char* s8t = (char*)As;
  #pragma unroll
  for (int j = 0; j < 4; ++j) {
    float mx = 0.f;
    #pragma unroll
    for (int nt = 0; nt < 4; ++nt) mx = fmaxf(mx, fabsf(hnew[nt][j]));
    mx = fmaxf(mx, __shfl_xor(mx, 1)); mx = fmaxf(mx, __shfl_xor(mx, 2));
    mx = fmaxf(mx, __shfl_xor(mx, 4)); mx = fmaxf(mx, __shfl_xor(mx, 8));
    float inv = mx > 0.f ? 127.f / mx : 0.f;
    int lrow = wv * 16 + g * 4 + j;
    #pragma unroll
    for (int nt = 0; nt < 4; ++nt)
      s8t[lrow * 64 + nt * 16 + r] = (char)(int)rintf(hnew[nt][j] * inv);
    if (r == 0) sscale[rowbase + lrow] = mx * (1.f / 127.f);
  }
  __syncthreads();
  {
    int row = t >> 2, c = t & 3;
    *reinterpret_cast<uint4*>(s8 + ((size_t)(rowbase + row)) * 64 + c * 16) =
        *reinterpret_cast<const uint4*>(s8t + row * 64 + c * 16);
  }
}

// ---------------- Set2Set ----------------
__global__ __launch_bounds__(256) void k_s2s(const float* __restrict__ state,
                                             const float* __restrict__ wihT,
                                             const float* __restrict__ whhT,
                                             const float* __restrict__ b_ih,
                                             const float* __restrict__ b_hh,
                                             const float* __restrict__ lin3_w,
                                             const float* __restrict__ lin3_b,
                                             float* __restrict__ d_out) {
  __shared__ float tile[64 * 65];
  __shared__ float qs[128], hhs[64], ccs[64], gates[256], attw[64];
  const int g = blockIdx.x, t = threadIdx.x;
  for (int c = t; c < 64 * 64; c += 256) {
    int row = c >> 6, col = c & 63;
    tile[row * 65 + col] = state[(size_t)(g * 64 + row) * 64 + col];
  }
  if (t < 128) qs[t] = 0.f;
  if (t < 64) { hhs[t] = 0.f; ccs[t] = 0.f; }
  __syncthreads();
  for (int it = 0; it < 3; ++it) {
    float acc = b_ih[t] + b_hh[t];
    for (int j = 0; j < 128; ++j) acc += qs[j] * wihT[j * 256 + t];
    for (int j = 0; j < 64; ++j)  acc += hhs[j] * whhT[j * 256 + t];
    gates[t] = acc;
    __syncthreads();
    if (t < 64) {
      float ci = sigm(gates[t]), cf = sigm(gates[64 + t]);
      float cg = tanhf(gates[128 + t]), co = sigm(gates[192 + t]);
      float c2 = cf * ccs[t] + ci * cg;
      ccs[t] = c2;
      float h2 = co * tanhf(c2);
      hhs[t] = h2; qs[t] = h2;
    }
    __syncthreads();
    if (t < 64) {
      float e = 0.f;
      for (int o = 0; o < 64; ++o) e += tile[t * 65 + o] * qs[o];
      float m = e;
      for (int off = 32; off; off >>= 1) m = fmaxf(m, __shfl_xor(m, off));
      float ex = expf(e - m);
      float s = ex;
      for (int off = 32; off; off >>= 1) s += __shfl_xor(s, off);
      attw[t] = ex / s;
    }
    __syncthreads();
    if (t < 64) {
      float racc = 0.f;
      for (int j = 0; j < 64; ++j) racc += attw[j] * tile[j * 65 + t];
      qs[64 + t] = racc;
    }
    __syncthreads();
  }
  if (t < 64) {
    float v = qs[t] * lin3_w[t] + qs[64 + t] * lin3_w[64 + t];
    for (int off = 32; off; off >>= 1) v += __shfl_xor(v, off);
    if (t == 0) d_out[g] = v + lin3_b[0];
  }
}

// ---------------- per-stem head ----------------
__global__ __launch_bounds__(512) void k_stem(const float* __restrict__ state,
                                              const int* __restrict__ stem_idx,
                                              const float* __restrict__ w1,
                                              const float* __restrict__ b1,
                                              const float* __restrict__ w2,
                                              const float* __restrict__ b2,
                                              float* __restrict__ d_out) {
  __shared__ float feat[64];
  __shared__ float hidl[512];
  const int t = threadIdx.x, s = blockIdx.x;
  if (t < 64) feat[t] = state[(size_t)stem_idx[s] * 64 + t];
  __syncthreads();
  {
    const float* wr = w1 + (size_t)t * 64;
    float a0 = 0.f, a1 = 0.f, a2 = 0.f, a3 = 0.f;
    #pragma unroll
    for (int i = 0; i < 64; i += 16) {
      float4 x0 = *reinterpret_cast<const float4*>(wr + i);
      float4 x1 = *reinterpret_cast<const float4*>(wr + i + 4);
      float4 x2 = *reinterpret_cast<const float4*>(wr + i + 8);
      float4 x3 = *reinterpret_cast<const float4*>(wr + i + 12);
      a0 += x0.x*feat[i]    + x0.y*feat[i+1]  + x0.z*feat[i+2]  + x0.w*feat[i+3];
      a1 += x1.x*feat[i+4]  + x1.y*feat[i+5]  + x1.z*feat[i+6]  + x1.w*feat[i+7];
      a2 += x2.x*feat[i+8]  + x2.y*feat[i+9]  + x2.z*feat[i+10] + x2.w*feat[i+11];
      a3 += x3.x*feat[i+12] + x3.y*feat[i+13] + x3.z*feat[i+14] + x3.w*feat[i+15];
    }
    hidl[t] = leaky(a0 + a1 + a2 + a3 + b1[t]);
  }
  __syncthreads();
  if (t < 4 * NOUT) {
    int o = t >> 2, q = t & 3;
    const float* wr = w2 + (size_t)o * 512 + q * 128;
    const float* hr = hidl + q * 128;
    float a0 = 0.f, a1 = 0.f, a2 = 0.f, a3 = 0.f;
    #pragma unroll
    for (int kk = 0; kk < 128; kk += 16) {
      float4 x0 = *reinterpret_cast<const float4*>(wr + kk);
      float4 x1 = *reinterpret_cast<const float4*>(wr + kk + 4);
      float4 x2 = *reinterpret_cast<const float4*>(wr + kk + 8);
      float4 x3 = *reinterpret_cast<const float4*>(wr + kk + 12);
      a0 += x0.x*hr[kk]    + x0.y*hr[kk+1]  + x0.z*hr[kk+2]  + x0.w*hr[kk+3];
      a1 += x1.x*hr[kk+4]  + x1.y*hr[kk+5]  + x1.z*hr[kk+6]  + x1.w*hr[kk+7];
      a2 += x2.x*hr[kk+8]  + x2.y*hr[kk+9]  + x2.z*hr[kk+10] + x2.w*hr[kk+11];
      a3 += x3.x*hr[kk+12] + x3.y*hr[kk+13] + x3.z*hr[kk+14] + x3.w*hr[kk+15];
    }
    float p = a0 + a1 + a2 + a3;
    p += __shfl_xor(p, 1); p += __shfl_xor(p, 2);
    if (q == 0) d_out[512 + (size_t)s * NOUT + o] = p + b2[o];
  }
}

extern "C" void kernel_launch(void* const* d_in, const int* in_sizes, int n_in,
                              void* d_out, int out_size, void* d_ws, size_t ws_size,
                              hipStream_t stream) {
  (void)in_sizes; (void)n_in; (void)out_size;
  if (ws_size < OFF_WT) return;

  // ---- all-int8 W: 4096 B/edge (+256 B scale in fixed SCL region) ----
  long pe8 = (long)((ws_size - OFF_WT) / 4096);
  if (pe8 > N_EDGES) pe8 = N_EDGES;
  pe8 &= ~63L;
  const int LIM8 = (int)pe8;
  const int TE = N_EDGES - LIM8;

  const float* x         = (const float*)d_in[0];
  const float* edge_attr = (const float*)d_in[1];
  const int*   eidx      = (const int*)d_in[2];
  const int*   stem_idx  = (const int*)d_in[4];
  const float* lin0_w = (const float*)d_in[5];
  const float* lin0_b = (const float*)d_in[6];
  const float* net_w1 = (const float*)d_in[7];
  const float* net_b1 = (const float*)d_in[8];
  const float* net_w2 = (const float*)d_in[9];
  const float* net_b2 = (const float*)d_in[10];
  const float* conv_root = (const float*)d_in[11];
  const float* conv_bias = (const float*)d_in[12];
  const float* gru_w_ih = (const float*)d_in[13];
  const float* gru_w_hh = (const float*)d_in[14];
  const float* gru_b_ih = (const float*)d_in[15];
  const float* gru_b_hh = (const float*)d_in[16];
  const float* lin1_w = (const float*)d_in[17];
  const float* lin1_b = (const float*)d_in[18];
  const float* lin2_w = (const float*)d_in[19];
  const float* lin2_b = (const float*)d_in[20];
  const float* s2s_w_ih = (const float*)d_in[21];
  const float* s2s_w_hh = (const float*)d_in[22];
  const float* s2s_b_ih = (const float*)d_in[23];
  const float* s2s_b_hh = (const float*)d_in[24];
  const float* lin3_w = (const float*)d_in[25];
  const float* lin3_b = (const float*)d_in[26];

  char* ws = (char*)d_ws;
  unsigned short* hid_p = (unsigned short*)(ws + OFF_HIDP);
  unsigned short* T2t  = (unsigned short*)(ws + OFF_T2T);
  float*          b2t  = (float*)(ws + OFF_B2T);
  float*          state= (float*)(ws + OFF_STATE);
  float*          agg  = (float*)(ws + OFF_AGG);
  float*          ideg = (float*)(ws + OFF_IDEG);
  int*            cnt  = (int*)(ws + OFF_CNT);
  int*            rp   = (int*)(ws + OFF_RP);
  int*            cur  = (int*)(ws + OFF_CUR);
  int*            src_p= (int*)(ws + OFF_SRCP);
  int*            dst_p= (int*)(ws + OFF_DSTP);
  int*            epos = (int*)(ws + OFF_EPOS);
  unsigned short* BW1f = (unsigned short*)(ws + OFF_BW1);
  unsigned short* BW2f = (unsigned short*)(ws + OFF_BW2);
  float*          wihT = (float*)(ws + OFF_WIH);
  float*          whhT = (float*)(ws + OFF_WHH);
  char*           s8   = (char*)(ws + OFF_S8);
  float*          sscale = (float*)(ws + OFF_SSC);
  float*          SCL  = (float*)(ws + OFF_SCL);
  unsigned char*  W8   = (unsigned char*)(ws + OFF_WT);
  float* out = (float*)d_out;

  const int* src = eidx;
  const int* dst = eidx + N_EDGES;

  hipMemsetAsync(cnt, 0, SZ_CNT, stream);
  k_deg<<<N_EDGES / 256, 256, 0, stream>>>(dst, cnt);
  k_scan<<<1, 1024, 0, stream>>>(cnt, rp, cur, ideg);
  k_permute<<<N_EDGES / 256, 256, 0, stream>>>(src, dst, cur, src_p, dst_p, epos);
  k_prep_t2<<<(WCOLS * NHID) / 256, 256, 0, stream>>>(net_w2, net_b2, T2t, b2t);
  k_prep_gru<<<112, 256, 0, stream>>>(conv_root, gru_w_hh, gru_w_ih, BW1f, BW2f);
  k_prep_s2s<<<192, 256, 0, stream>>>(s2s_w_ih, s2s_w_hh, wihT, whhT);
  k_lin0<<<(N_NODES * DIM) / 256, 256, 0, stream>>>(x, lin0_w, lin0_b, state);
  k_qstate<<<N_NODES / 4, 256, 0, stream>>>(state, s8, sscale);
  k_hidden<<<(N_EDGES * NHID) / 256, 256, 0, stream>>>(edge_attr, net_w1, net_b1,
                                                       epos, hid_p);
  if (LIM8 > 0) {   // split into two dispatches: halves wgemm's top-5 footprint,
                    // exposes the loop kernels in the profile
    long half = ((long)LIM8 / 2) & ~63L;
    if (half > 0)
      k_wgemm<<<dim3(WCOLS / 64, half / 64), 256, 0, stream>>>(hid_p, T2t, b2t, W8, SCL);
    if (LIM8 - half > 0)
      k_wgemm<<<dim3(WCOLS / 64, (LIM8 - half) / 64), 256, 0, stream>>>(
          hid_p + (size_t)half * NHID, T2t, b2t,
          W8 + (size_t)half * 4096, SCL + (size_t)half * 64);
  }

  for (int s = 0; s < 12; ++s) {
    k_msg_csr<<<N_NODES / 4, 256, 0, stream>>>(W8, SCL, s8, sscale, LIM8,
                                               rp, src_p, ideg, agg);
    if (TE > 0)
      k_wmsg<<<(TE + 63) / 64, 256, 0, stream>>>(hid_p + (size_t)LIM8 * NHID, T2t, b2t,
                                                 state, src_p, dst_p, ideg, LIM8, agg);
    k_gru<<<N_NODES / 64, 256, 0, stream>>>(agg, state, BW1f, BW2f, conv_bias,
                                            gru_b_ih, gru_b_hh, s8, sscale);
  }

  k_s2s<<<NGRAPH, 256, 0, stream>>>(state, wihT, whhT, s2s_b_ih, s2s_b_hh,
                                    lin3_w, lin3_b, out);
  k_stem<<<NSTEM, 512, 0, stream>>>(state, stem_idx, lin1_w, lin1_b,
                                    lin2_w, lin2_b, out);
}

// Round 14
// 2021.041 us; speedup vs baseline: 1.0541x; 1.0541x over previous
//
#include <hip/hip_runtime.h>
#include <hip/hip_bf16.h>

#define N_NODES   32768
#define N_EDGES   65536
#define NGRAPH    512
#define DIM       64
#define NFEAT     14
#define NHID      128
#define WCOLS     4096
#define NSTEM     1024
#define NOUT      105

typedef __attribute__((ext_vector_type(8))) short short8;
typedef __attribute__((ext_vector_type(4))) float f32x4;

__device__ __forceinline__ float bf2f(unsigned int u16) {
  union { unsigned int i; float f; } c; c.i = u16 << 16; return c.f;
}
__device__ __forceinline__ unsigned short f2bf(float f) {
  union { float f; unsigned int i; } c; c.f = f;
  return (unsigned short)((c.i + 0x7fffu + ((c.i >> 16) & 1u)) >> 16);
}
__device__ __forceinline__ float leaky(float x) { return x > 0.f ? x : 0.01f * x; }
__device__ __forceinline__ float sigm(float x) { return 1.f / (1.f + expf(-x)); }

constexpr size_t ALN(size_t x) { return (x + 255) & ~(size_t)255; }

// ---------------- fixed workspace layout (~47 MB) ----------------
constexpr size_t OFF_HIDP = 0;
constexpr size_t SZ_HIDP  = (size_t)N_EDGES * NHID * 2;       // 16 MB bf16 (CSR order)
constexpr size_t OFF_T2T  = ALN(OFF_HIDP + SZ_HIDP);
constexpr size_t SZ_T2T   = (size_t)WCOLS * NHID * 2;         // 1 MB
constexpr size_t OFF_B2T  = ALN(OFF_T2T + SZ_T2T);
constexpr size_t SZ_B2T   = (size_t)WCOLS * 4;
constexpr size_t OFF_STATE= ALN(OFF_B2T + SZ_B2T);
constexpr size_t SZ_STATE = (size_t)N_NODES * DIM * 4;        // 8 MB
constexpr size_t OFF_AGG  = ALN(OFF_STATE + SZ_STATE);
constexpr size_t SZ_AGG   = SZ_STATE;                         // 8 MB
constexpr size_t OFF_IDEG = ALN(OFF_AGG + SZ_AGG);
constexpr size_t SZ_IDEG  = (size_t)N_NODES * 4;
constexpr size_t OFF_CNT  = ALN(OFF_IDEG + SZ_IDEG);
constexpr size_t SZ_CNT   = (size_t)N_NODES * 4;
constexpr size_t OFF_RP   = ALN(OFF_CNT + SZ_CNT);
constexpr size_t SZ_RP    = (size_t)(N_NODES + 1) * 4;
constexpr size_t OFF_CUR  = ALN(OFF_RP + SZ_RP);
constexpr size_t SZ_CUR   = (size_t)N_NODES * 4;
constexpr size_t OFF_SRCP = ALN(OFF_CUR + SZ_CUR);
constexpr size_t SZ_SRCP  = (size_t)N_EDGES * 4;
constexpr size_t OFF_DSTP = ALN(OFF_SRCP + SZ_SRCP);
constexpr size_t SZ_DSTP  = (size_t)N_EDGES * 4;
constexpr size_t OFF_EPOS = ALN(OFF_DSTP + SZ_DSTP);
constexpr size_t SZ_EPOS  = (size_t)N_EDGES * 4;
constexpr size_t OFF_BW1  = ALN(OFF_EPOS + SZ_EPOS);
constexpr size_t SZ_BW1   = 256 * 64 * 2;                  // [n=256][k=64] bf16 : root|w_hh
constexpr size_t OFF_BW2  = ALN(OFF_BW1 + SZ_BW1);
constexpr size_t SZ_BW2   = 192 * 64 * 2;                  // [n=192][k=64] bf16 : w_ih
constexpr size_t OFF_WIH  = ALN(OFF_BW2 + SZ_BW2);
constexpr size_t SZ_WIH   = 128 * 256 * 4;
constexpr size_t OFF_WHH  = ALN(OFF_WIH + SZ_WIH);
constexpr size_t SZ_WHH   = 64 * 256 * 4;
constexpr size_t OFF_S8   = ALN(OFF_WHH + SZ_WHH);
constexpr size_t SZ_S8    = (size_t)N_NODES * 64;             // 2 MB int8 state
constexpr size_t OFF_SSC  = ALN(OFF_S8 + SZ_S8);
constexpr size_t SZ_SSC   = (size_t)N_NODES * 4;
constexpr size_t OFF_SCL  = ALN(OFF_SSC + SZ_SSC);
constexpr size_t SZ_SCL   = (size_t)N_EDGES * 64 * 2;         // 8 MB bf16 scales
constexpr size_t OFF_WT   = ALN(OFF_SCL + SZ_SCL);            // W8 base

// ---------------- prep kernels ----------------
__global__ void k_deg(const int* __restrict__ dst, int* __restrict__ cnt) {
  int e = blockIdx.x * 256 + threadIdx.x;
  atomicAdd(&cnt[dst[e]], 1);
}
__global__ __launch_bounds__(1024) void k_scan(const int* __restrict__ cnt,
                                               int* __restrict__ rp,
                                               int* __restrict__ cur,
                                               float* __restrict__ ideg) {
  __shared__ int part[1024];
  const int t = threadIdx.x, base = t * 32;
  int s = 0;
  for (int i = 0; i < 32; ++i) s += cnt[base + i];
  part[t] = s;
  __syncthreads();
  for (int off = 1; off < 1024; off <<= 1) {
    int v = (t >= off) ? part[t - off] : 0;
    __syncthreads();
    part[t] += v;
    __syncthreads();
  }
  int run = part[t] - s;
  for (int i = 0; i < 32; ++i) {
    int c = cnt[base + i];
    rp[base + i] = run; cur[base + i] = run;
    ideg[base + i] = 1.0f / fmaxf((float)c, 1.0f);
    run += c;
  }
  if (t == 1023) rp[N_NODES] = run;
}
__global__ void k_permute(const int* __restrict__ src, const int* __restrict__ dst,
                          int* __restrict__ cur, int* __restrict__ src_p,
                          int* __restrict__ dst_p, int* __restrict__ epos) {
  int e = blockIdx.x * 256 + threadIdx.x;
  int d = dst[e];
  int p = atomicAdd(&cur[d], 1);
  src_p[p] = src[e]; dst_p[p] = d; epos[e] = p;
}
// T2t[r=o*64+i][h] = net_w2[(i*64+o)][h]; b2t[r] = net_b2[i*64+o]
__global__ void k_prep_t2(const float* __restrict__ w2, const float* __restrict__ b2,
                          unsigned short* __restrict__ T2t, float* __restrict__ b2t) {
  int gid = blockIdx.x * 256 + threadIdx.x;
  int r = gid >> 7, h = gid & 127;
  int srow = (r & 63) * 64 + (r >> 6);
  T2t[gid] = f2bf(w2[(size_t)srow * 128 + h]);
  if (h == 0) b2t[r] = b2[srow];
}
__global__ void k_prep_gru(const float* __restrict__ root, const float* __restrict__ whh,
                           const float* __restrict__ wih,
                           unsigned short* __restrict__ BW1, unsigned short* __restrict__ BW2) {
  int gid = blockIdx.x * 256 + threadIdx.x;
  if (gid >= 64 * 448) return;
  int i = gid / 448, c = gid % 448;
  if (c < 64)        BW1[c * 64 + i] = f2bf(root[i * 64 + c]);
  else if (c < 256)  BW1[c * 64 + i] = f2bf(whh[(c - 64) * 64 + i]);
  else               BW2[(c - 256) * 64 + i] = f2bf(wih[(c - 256) * 64 + i]);
}
__global__ void k_prep_s2s(const float* __restrict__ wih, const float* __restrict__ whh,
                           float* __restrict__ wihT, float* __restrict__ whhT) {
  int gid = blockIdx.x * 256 + threadIdx.x;
  if (gid < 32768) { int j = gid >> 8, k = gid & 255; wihT[gid] = wih[k * 128 + j]; }
  else { int g2 = gid - 32768; int j = g2 >> 8, k = g2 & 255; whhT[g2] = whh[k * 64 + j]; }
}
__global__ void k_lin0(const float* __restrict__ x, const float* __restrict__ w,
                       const float* __restrict__ b, float* __restrict__ state) {
  int gid = blockIdx.x * 256 + threadIdx.x;
  int n = gid >> 6, o = gid & 63;
  float acc = b[o];
  #pragma unroll
  for (int f = 0; f < NFEAT; ++f) acc += x[(size_t)n * NFEAT + f] * w[o * NFEAT + f];
  state[gid] = leaky(acc);
}
__global__ void k_hidden(const float* __restrict__ ea, const float* __restrict__ w1,
                         const float* __restrict__ b1, const int* __restrict__ epos,
                         unsigned short* __restrict__ hid_p) {
  int gid = blockIdx.x * 256 + threadIdx.x;
  int e = gid >> 7, h = gid & 127;
  float acc = b1[h];
  #pragma unroll
  for (int d = 0; d < 4; ++d) acc += ea[(size_t)e * 4 + d] * w1[h * 4 + d];
  hid_p[(size_t)epos[e] * 128 + h] = f2bf(leaky(acc));
}
// quantize state rows to int8 (wave per node)
__global__ __launch_bounds__(256) void k_qstate(const float* __restrict__ state,
                                                char* __restrict__ s8,
                                                float* __restrict__ sscale) {
  __shared__ char q8[4][64];
  __shared__ float scs[4];
  const int t = threadIdx.x, wv = t >> 6, ln = t & 63;
  const int n = blockIdx.x * 4 + wv;
  float v = state[(size_t)n * 64 + ln];
  float m = fabsf(v);
  #pragma unroll
  for (int off = 1; off < 64; off <<= 1) m = fmaxf(m, __shfl_xor(m, off));
  float inv = m > 0.f ? 127.f / m : 0.f;
  q8[wv][ln] = (char)(int)rintf(v * inv);
  if (ln == 0) scs[wv] = m * (1.f / 127.f);
  __syncthreads();
  if (t < 64) {
    int w2 = t >> 4, c = t & 15;
    reinterpret_cast<int*>(s8)[((size_t)(blockIdx.x * 4 + w2)) * 16 + c] =
        reinterpret_cast<const int*>(q8[w2])[c];
  }
  if (t < 4) sscale[blockIdx.x * 4 + t] = scs[t];
}

// ---------------- W build GEMM: 8 o-tiles/block, register W-line, full-line writes ----
// W8[e*4096 + (i>>4)*1024 + o*16 + (i&15)] ; SCLh[e*64 + o] (bf16)
#define WG_PAD 136
__global__ __launch_bounds__(256) void k_wgemm8(const unsigned short* __restrict__ A,
                                                const unsigned short* __restrict__ Bt,
                                                const float* __restrict__ b2t,
                                                unsigned char* __restrict__ W8,
                                                unsigned short* __restrict__ SCLh) {
  __shared__ __align__(16) unsigned short As[64 * WG_PAD];   // 17.4 KB
  __shared__ __align__(16) unsigned short Bs[64 * WG_PAD];   // 17.4 KB
  __shared__ __align__(16) char pk[64][64];                  // 4 KB
  __shared__ unsigned short sclh[64][8];                     // 1 KB
  const int og = blockIdx.x, mb = blockIdx.y, t = threadIdx.x;
  #pragma unroll
  for (int j = 0; j < 4; ++j) {            // stage A once
    int c = t + 256 * j;
    int row = c >> 4, col8 = (c & 15) * 8;
    *reinterpret_cast<uint4*>(&As[row * WG_PAD + col8]) =
        *reinterpret_cast<const uint4*>(A + (size_t)(mb * 64 + row) * 128 + col8);
  }
  const int wv = t >> 6, ln = t & 63, r = ln & 15, g = ln >> 4;
  uint4 wline[8];
  #pragma unroll
  for (int obi = 0; obi < 8; ++obi) {
    const int nb = og * 8 + obi;
    #pragma unroll
    for (int j = 0; j < 4; ++j) {          // stage B tile for this o
      int c = t + 256 * j;
      int row = c >> 4, col8 = (c & 15) * 8;
      *reinterpret_cast<uint4*>(&Bs[row * WG_PAD + col8]) =
          *reinterpret_cast<const uint4*>(Bt + (size_t)(nb * 64 + row) * 128 + col8);
    }
    __syncthreads();                       // Bs ready; prev pk reads done
    f32x4 acc[4] = {};
    #pragma unroll
    for (int ks = 0; ks < 4; ++ks) {
      int kk = ks * 32 + g * 8;
      short8 a = *reinterpret_cast<const short8*>(&As[(wv * 16 + r) * WG_PAD + kk]);
      #pragma unroll
      for (int nt = 0; nt < 4; ++nt) {
        short8 b = *reinterpret_cast<const short8*>(&Bs[(nt * 16 + r) * WG_PAD + kk]);
        acc[nt] = __builtin_amdgcn_mfma_f32_16x16x32_bf16(a, b, acc[nt], 0, 0, 0);
      }
    }
    float bias[4];
    #pragma unroll
    for (int nt = 0; nt < 4; ++nt) bias[nt] = b2t[nb * 64 + nt * 16 + r];
    #pragma unroll
    for (int j = 0; j < 4; ++j) {
      int e_l = wv * 16 + g * 4 + j;
      float w[4], m = 0.f;
      #pragma unroll
      for (int nt = 0; nt < 4; ++nt) { w[nt] = acc[nt][j] + bias[nt]; m = fmaxf(m, fabsf(w[nt])); }
      m = fmaxf(m, __shfl_xor(m, 1)); m = fmaxf(m, __shfl_xor(m, 2));
      m = fmaxf(m, __shfl_xor(m, 4)); m = fmaxf(m, __shfl_xor(m, 8));
      float inv = m > 0.f ? 127.f / m : 0.f;
      #pragma unroll
      for (int nt = 0; nt < 4; ++nt)
        pk[e_l][nt * 16 + r] = (char)(int)rintf(w[nt] * inv);
      if (r == 0) sclh[e_l][obi] = f2bf(m * (1.f / 127.f));
    }
    __syncthreads();                       // pk written
    wline[obi] = *reinterpret_cast<const uint4*>(&pk[t >> 2][(t & 3) * 16]);
  }
  {   // one full 128-B line per thread: (e_l, jc), o-range [og*8, og*8+8)
    unsigned char* dstp = W8 + ((size_t)(mb * 64) + (t >> 2)) * 4096 + (t & 3) * 1024 + og * 128;
    #pragma unroll
    for (int q = 0; q < 8; ++q)
      reinterpret_cast<uint4*>(dstp)[q] = wline[q];
  }
  if (t < 64) {   // 16-B bf16 scale piece
    *reinterpret_cast<uint4*>(SCLh + ((size_t)(mb * 64) + t) * 64 + og * 8) =
        *reinterpret_cast<const uint4*>(&sclh[t][0]);
  }
}

// ---------------- per-step msg: CSR gather, int8 x int8 via sdot4 (r9) ----------------
__device__ __forceinline__ int dot64(const uint4* __restrict__ wp, const int* __restrict__ s) {
  int u = 0;
  #pragma unroll
  for (int j = 0; j < 4; ++j) {
    uint4 v = wp[j * 64];                       // +j*1024 bytes
    u = __builtin_amdgcn_sdot4((int)v.x, s[j * 4 + 0], u, false);
    u = __builtin_amdgcn_sdot4((int)v.y, s[j * 4 + 1], u, false);
    u = __builtin_amdgcn_sdot4((int)v.z, s[j * 4 + 2], u, false);
    u = __builtin_amdgcn_sdot4((int)v.w, s[j * 4 + 3], u, false);
  }
  return u;
}

__global__ __launch_bounds__(256) void k_msg_csr(const unsigned char* __restrict__ W8,
                                                 const unsigned short* __restrict__ SCLh,
                                                 const char* __restrict__ s8,
                                                 const float* __restrict__ sscale,
                                                 int lim8,
                                                 const int* __restrict__ rp,
                                                 const int* __restrict__ src_p,
                                                 const float* __restrict__ ideg,
                                                 float* __restrict__ agg) {
  const int wv = threadIdx.x >> 6, ln = threadIdx.x & 63;
  const int d = blockIdx.x * 4 + wv;
  int k0 = rp[d], k1 = rp[d + 1];
  if (k1 > lim8) k1 = lim8;            // tail edges handled by k_wmsg
  float acc = 0.f;
  int k = k0;
  for (; k + 2 <= k1; k += 2) {
    const uint4* wA = reinterpret_cast<const uint4*>(W8 + (size_t)k * 4096 + ln * 16);
    const uint4* wB = reinterpret_cast<const uint4*>(W8 + (size_t)(k + 1) * 4096 + ln * 16);
    int sA = __builtin_amdgcn_readfirstlane(src_p[k]);
    int sB = __builtin_amdgcn_readfirstlane(src_p[k + 1]);
    const int* rA = reinterpret_cast<const int*>(s8 + (size_t)sA * 64);
    const int* rB = reinterpret_cast<const int*>(s8 + (size_t)sB * 64);
    float fA = bf2f(SCLh[(size_t)k * 64 + ln]) * sscale[sA];
    float fB = bf2f(SCLh[(size_t)k * 64 + 64 + ln]) * sscale[sB];
    int uA = dot64(wA, rA);
    int uB = dot64(wB, rB);
    acc = fmaf((float)uA, fA, acc);
    acc = fmaf((float)uB, fB, acc);
  }
  if (k < k1) {
    const uint4* wA = reinterpret_cast<const uint4*>(W8 + (size_t)k * 4096 + ln * 16);
    int sA = __builtin_amdgcn_readfirstlane(src_p[k]);
    const int* rA = reinterpret_cast<const int*>(s8 + (size_t)sA * 64);
    float fA = bf2f(SCLh[(size_t)k * 64 + ln]) * sscale[sA];
    acc = fmaf((float)dot64(wA, rA), fA, acc);
  }
  agg[(size_t)d * 64 + ln] = acc * ideg[d];
}

// ---------------- fallback transient (only if ws too small): adds on top ----------------
#define WM_PAD 136
__global__ __launch_bounds__(256) void k_wmsg(const unsigned short* __restrict__ hid,
                                              const unsigned short* __restrict__ T2t,
                                              const float* __restrict__ b2t,
                                              const float* __restrict__ state,
                                              const int* __restrict__ srcs,
                                              const int* __restrict__ dsts,
                                              const float* __restrict__ ideg,
                                              int e0,
                                              float* __restrict__ agg) {
  __shared__ __align__(16) unsigned short As[64 * WM_PAD];
  __shared__ __align__(16) unsigned short Bs[2][64 * WM_PAD];
  __shared__ __align__(16) float Ss[64][68];
  __shared__ int dstl[64]; __shared__ float idgl[64];
  __shared__ int srcl[64];
  const int t = threadIdx.x;
  const int eb = blockIdx.x * 64;
  if (t < 64) {
    int e = e0 + eb + t;
    srcl[t] = srcs[e];
    int d = dsts[e]; dstl[t] = d; idgl[t] = ideg[d];
  }
  __syncthreads();
  #pragma unroll
  for (int j = 0; j < 4; ++j) {
    int c = t + 256 * j;
    int row = c >> 4, col8 = (c & 15) * 8;
    *reinterpret_cast<uint4*>(&As[row * WM_PAD + col8]) =
        *reinterpret_cast<const uint4*>(hid + (size_t)(eb + row) * 128 + col8);
  }
  #pragma unroll
  for (int j = 0; j < 4; ++j) {
    int c = t + 256 * j;
    int row = c >> 4, q = (c & 15) * 4;
    *reinterpret_cast<float4*>(&Ss[row][q]) =
        *reinterpret_cast<const float4*>(state + (size_t)srcl[row] * 64 + q);
  }
  #pragma unroll
  for (int j = 0; j < 4; ++j) {
    int c = t + 256 * j;
    int row = c >> 4, col8 = (c & 15) * 8;
    *reinterpret_cast<uint4*>(&Bs[0][row * WM_PAD + col8]) =
        *reinterpret_cast<const uint4*>(T2t + (size_t)row * 128 + col8);
  }
  __syncthreads();
  const int wv = t >> 6, ln = t & 63, r = ln & 15, g = ln >> 4;
  for (int nb = 0; nb < 64; ++nb) {
    const int cur = nb & 1;
    if (nb + 1 < 64) {
      #pragma unroll
      for (int j = 0; j < 4; ++j) {
        int c = t + 256 * j;
        int row = c >> 4, col8 = (c & 15) * 8;
        *reinterpret_cast<uint4*>(&Bs[cur ^ 1][row * WM_PAD + col8]) =
            *reinterpret_cast<const uint4*>(T2t + (size_t)((nb + 1) * 64 + row) * 128 + col8);
      }
    }
    f32x4 acc[4] = {};
    #pragma unroll
    for (int ks = 0; ks < 4; ++ks) {
      int kk = ks * 32 + g * 8;
      short8 a = *reinterpret_cast<const short8*>(&As[(wv * 16 + r) * WM_PAD + kk]);
      #pragma unroll
      for (int nt = 0; nt < 4; ++nt) {
        short8 b = *reinterpret_cast<const short8*>(&Bs[cur][(nt * 16 + r) * WM_PAD + kk]);
        acc[nt] = __builtin_amdgcn_mfma_f32_16x16x32_bf16(a, b, acc[nt], 0, 0, 0);
      }
    }
    float bias[4];
    #pragma unroll
    for (int nt = 0; nt < 4; ++nt) bias[nt] = b2t[nb * 64 + nt * 16 + r];
    float pj[4];
    #pragma unroll
    for (int j = 0; j < 4; ++j) {
      int row = wv * 16 + g * 4 + j;
      float p = 0.f;
      #pragma unroll
      for (int nt = 0; nt < 4; ++nt)
        p += (acc[nt][j] + bias[nt]) * Ss[row][nt * 16 + r];
      pj[j] = p;
    }
    #pragma unroll
    for (int j = 0; j < 4; ++j) {
      float p = pj[j];
      p += __shfl_xor(p, 1); p += __shfl_xor(p, 2);
      p += __shfl_xor(p, 4); p += __shfl_xor(p, 8);
      pj[j] = p;
    }
    if (r == 0) {
      #pragma unroll
      for (int j = 0; j < 4; ++j) {
        int row = wv * 16 + g * 4 + j;
        atomicAdd(&agg[(size_t)dstl[row] * 64 + nb], pj[j] * idgl[row]);
      }
    }
    __syncthreads();
  }
}

// ---------------- per-step fused: root GEMM + m + GRU gates + state re-quant (r9) --------
#define KPAD 72
__global__ __launch_bounds__(512, 1) void k_gru(const float* __restrict__ agg,
                                                float* __restrict__ state,
                                                const unsigned short* __restrict__ BW1,
                                                const unsigned short* __restrict__ BW2,
                                                const float* __restrict__ conv_bias,
                                                const float* __restrict__ b_ih,
                                                const float* __restrict__ b_hh,
                                                char* __restrict__ s8,
                                                float* __restrict__ sscale) {
  __shared__ __align__(16) unsigned short As[128 * KPAD];
  __shared__ __align__(16) unsigned short Ms[128 * KPAD];
  __shared__ __align__(16) unsigned short B1s[256 * KPAD];
  __shared__ __align__(16) unsigned short B2s[192 * KPAD];
  const int t = threadIdx.x;
  const int rowbase = blockIdx.x * 128;
  #pragma unroll
  for (int j = 0; j < 2; ++j) {
    int c = t + 512 * j;
    int row = c >> 3, col8 = (c & 7) * 8;
    const float* sp = state + (size_t)(rowbase + row) * 64 + col8;
    float4 f0 = *reinterpret_cast<const float4*>(sp);
    float4 f1 = *reinterpret_cast<const float4*>(sp + 4);
    short8 hv;
    hv[0] = (short)f2bf(f0.x); hv[1] = (short)f2bf(f0.y);
    hv[2] = (short)f2bf(f0.z); hv[3] = (short)f2bf(f0.w);
    hv[4] = (short)f2bf(f1.x); hv[5] = (short)f2bf(f1.y);
    hv[6] = (short)f2bf(f1.z); hv[7] = (short)f2bf(f1.w);
    *reinterpret_cast<short8*>(&As[row * KPAD + col8]) = hv;
  }
  #pragma unroll
  for (int j = 0; j < 4; ++j) {
    int c = t + 512 * j;
    int row = c >> 3, col8 = (c & 7) * 8;
    *reinterpret_cast<uint4*>(&B1s[row * KPAD + col8]) =
        *reinterpret_cast<const uint4*>(BW1 + row * 64 + col8);
  }
  #pragma unroll
  for (int j = 0; j < 3; ++j) {
    int c = t + 512 * j;
    int row = c >> 3, col8 = (c & 7) * 8;
    *reinterpret_cast<uint4*>(&B2s[row * KPAD + col8]) =
        *reinterpret_cast<const uint4*>(BW2 + row * 64 + col8);
  }
  __syncthreads();
  const int wv = t >> 6, ln = t & 63, r = ln & 15, g = ln >> 4;
  f32x4 acc1[16] = {};
  #pragma unroll
  for (int ks = 0; ks < 2; ++ks) {
    int kk = ks * 32 + g * 8;
    short8 a = *reinterpret_cast<const short8*>(&As[(wv * 16 + r) * KPAD + kk]);
    #pragma unroll
    for (int nt = 0; nt < 16; ++nt) {
      short8 b = *reinterpret_cast<const short8*>(&B1s[(nt * 16 + r) * KPAD + kk]);
      acc1[nt] = __builtin_amdgcn_mfma_f32_16x16x32_bf16(a, b, acc1[nt], 0, 0, 0);
    }
  }
  #pragma unroll
  for (int nt = 0; nt < 4; ++nt) {
    int col = nt * 16 + r;
    float cb = conv_bias[col];
    #pragma unroll
    for (int j = 0; j < 4; ++j) {
      int lrow = wv * 16 + g * 4 + j;
      float mv = agg[(size_t)(rowbase + lrow) * 64 + col] + acc1[nt][j] + cb;
      Ms[lrow * KPAD + col] = f2bf(leaky(mv));
    }
  }
  __syncthreads();
  f32x4 acc2[12] = {};
  #pragma unroll
  for (int ks = 0; ks < 2; ++ks) {
    int kk = ks * 32 + g * 8;
    short8 a = *reinterpret_cast<const short8*>(&Ms[(wv * 16 + r) * KPAD + kk]);
    #pragma unroll
    for (int nt = 0; nt < 12; ++nt) {
      short8 b = *reinterpret_cast<const short8*>(&B2s[(nt * 16 + r) * KPAD + kk]);
      acc2[nt] = __builtin_amdgcn_mfma_f32_16x16x32_bf16(a, b, acc2[nt], 0, 0, 0);
    }
  }
  float hnew[4][4];
  #pragma unroll
  for (int nt = 0; nt < 4; ++nt) {
    int o = nt * 16 + r;
    float bir = b_ih[o],       bhr = b_hh[o];
    float biz = b_ih[64 + o],  bhz = b_hh[64 + o];
    float bin = b_ih[128 + o], bhn = b_hh[128 + o];
    #pragma unroll
    for (int j = 0; j < 4; ++j) {
      size_t gidx = (size_t)(rowbase + wv * 16 + g * 4 + j) * 64 + o;
      float rr = sigm(acc2[nt][j] + bir + acc1[4 + nt][j] + bhr);
      float zz = sigm(acc2[4 + nt][j] + biz + acc1[8 + nt][j] + bhz);
      float nn = tanhf(acc2[8 + nt][j] + bin + rr * (acc1[12 + nt][j] + bhn));
      float hold = state[gidx];
      float hv = (1.f - zz) * nn + zz * hold;
      state[gidx] = hv;
      hnew[nt][j] = hv;
    }
  }
  // re-quantize new state rows to int8 (As LDS reused as byte tile)
  char* s8t = (char*)As;
  #pragma unroll
  for (int j = 0; j < 4; ++j) {
    float mx = 0.f;
    #pragma unroll
    for (int nt = 0; nt < 4; ++nt) mx = fmaxf(mx, fabsf(hnew[nt][j]));
    mx = fmaxf(mx, __shfl_xor(mx, 1)); mx = fmaxf(mx, __shfl_xor(mx, 2));
    mx = fmaxf(mx, __shfl_xor(mx, 4)); mx = fmaxf(mx, __shfl_xor(mx, 8));
    float inv = mx > 0.f ? 127.f / mx : 0.f;
    int lrow = wv * 16 + g * 4 + j;
    #pragma unroll
    for (int nt = 0; nt < 4; ++nt)
      s8t[lrow * 64 + nt * 16 + r] = (char)(int)rintf(hnew[nt][j] * inv);
    if (r == 0) sscale[rowbase + lrow] = mx * (1.f / 127.f);
  }
  __syncthreads();
  {
    int row = t >> 2, c = t & 3;
    *reinterpret_cast<uint4*>(s8 + ((size_t)(rowbase + row)) * 64 + c * 16) =
        *reinterpret_cast<const uint4*>(s8t + row * 64 + c * 16);
  }
}

// ---------------- Set2Set ----------------
__global__ __launch_bounds__(256) void k_s2s(const float* __restrict__ state,
                                             const float* __restrict__ wihT,
                                             const float* __restrict__ whhT,
                                             const float* __restrict__ b_ih,
                                             const float* __restrict__ b_hh,
                                             const float* __restrict__ lin3_w,
                                             const float* __restrict__ lin3_b,
                                             float* __restrict__ d_out) {
  __shared__ float tile[64 * 65];
  __shared__ float qs[128], hhs[64], ccs[64], gates[256], attw[64];
  const int g = blockIdx.x, t = threadIdx.x;
  for (int c = t; c < 64 * 64; c += 256) {
    int row = c >> 6, col = c & 63;
    tile[row * 65 + col] = state[(size_t)(g * 64 + row) * 64 + col];
  }
  if (t < 128) qs[t] = 0.f;
  if (t < 64) { hhs[t] = 0.f; ccs[t] = 0.f; }
  __syncthreads();
  for (int it = 0; it < 3; ++it) {
    float acc = b_ih[t] + b_hh[t];
    for (int j = 0; j < 128; ++j) acc += qs[j] * wihT[j * 256 + t];
    for (int j = 0; j < 64; ++j)  acc += hhs[j] * whhT[j * 256 + t];
    gates[t] = acc;
    __syncthreads();
    if (t < 64) {
      float ci = sigm(gates[t]), cf = sigm(gates[64 + t]);
      float cg = tanhf(gates[128 + t]), co = sigm(gates[192 + t]);
      float c2 = cf * ccs[t] + ci * cg;
      ccs[t] = c2;
      float h2 = co * tanhf(c2);
      hhs[t] = h2; qs[t] = h2;
    }
    __syncthreads();
    if (t < 64) {
      float e = 0.f;
      for (int o = 0; o < 64; ++o) e += tile[t * 65 + o] * qs[o];
      float m = e;
      for (int off = 32; off; off >>= 1) m = fmaxf(m, __shfl_xor(m, off));
      float ex = expf(e - m);
      float s = ex;
      for (int off = 32; off; off >>= 1) s += __shfl_xor(s, off);
      attw[t] = ex / s;
    }
    __syncthreads();
    if (t < 64) {
      float racc = 0.f;
      for (int j = 0; j < 64; ++j) racc += attw[j] * tile[j * 65 + t];
      qs[64 + t] = racc;
    }
    __syncthreads();
  }
  if (t < 64) {
    float v = qs[t] * lin3_w[t] + qs[64 + t] * lin3_w[64 + t];
    for (int off = 32; off; off >>= 1) v += __shfl_xor(v, off);
    if (t == 0) d_out[g] = v + lin3_b[0];
  }
}

// ---------------- per-stem head ----------------
__global__ __launch_bounds__(512) void k_stem(const float* __restrict__ state,
                                              const int* __restrict__ stem_idx,
                                              const float* __restrict__ w1,
                                              const float* __restrict__ b1,
                                              const float* __restrict__ w2,
                                              const float* __restrict__ b2,
                                              float* __restrict__ d_out) {
  __shared__ float feat[64];
  __shared__ float hidl[512];
  const int t = threadIdx.x, s = blockIdx.x;
  if (t < 64) feat[t] = state[(size_t)stem_idx[s] * 64 + t];
  __syncthreads();
  {
    const float* wr = w1 + (size_t)t * 64;
    float a0 = 0.f, a1 = 0.f, a2 = 0.f, a3 = 0.f;
    #pragma unroll
    for (int i = 0; i < 64; i += 16) {
      float4 x0 = *reinterpret_cast<const float4*>(wr + i);
      float4 x1 = *reinterpret_cast<const float4*>(wr + i + 4);
      float4 x2 = *reinterpret_cast<const float4*>(wr + i + 8);
      float4 x3 = *reinterpret_cast<const float4*>(wr + i + 12);
      a0 += x0.x*feat[i]    + x0.y*feat[i+1]  + x0.z*feat[i+2]  + x0.w*feat[i+3];
      a1 += x1.x*feat[i+4]  + x1.y*feat[i+5]  + x1.z*feat[i+6]  + x1.w*feat[i+7];
      a2 += x2.x*feat[i+8]  + x2.y*feat[i+9]  + x2.z*feat[i+10] + x2.w*feat[i+11];
      a3 += x3.x*feat[i+12] + x3.y*feat[i+13] + x3.z*feat[i+14] + x3.w*feat[i+15];
    }
    hidl[t] = leaky(a0 + a1 + a2 + a3 + b1[t]);
  }
  __syncthreads();
  if (t < 4 * NOUT) {
    int o = t >> 2, q = t & 3;
    const float* wr = w2 + (size_t)o * 512 + q * 128;
    const float* hr = hidl + q * 128;
    float a0 = 0.f, a1 = 0.f, a2 = 0.f, a3 = 0.f;
    #pragma unroll
    for (int kk = 0; kk < 128; kk += 16) {
      float4 x0 = *reinterpret_cast<const float4*>(wr + kk);
      float4 x1 = *reinterpret_cast<const float4*>(wr + kk + 4);
      float4 x2 = *reinterpret_cast<const float4*>(wr + kk + 8);
      float4 x3 = *reinterpret_cast<const float4*>(wr + kk + 12);
      a0 += x0.x*hr[kk]    + x0.y*hr[kk+1]  + x0.z*hr[kk+2]  + x0.w*hr[kk+3];
      a1 += x1.x*hr[kk+4]  + x1.y*hr[kk+5]  + x1.z*hr[kk+6]  + x1.w*hr[kk+7];
      a2 += x2.x*hr[kk+8]  + x2.y*hr[kk+9]  + x2.z*hr[kk+10] + x2.w*hr[kk+11];
      a3 += x3.x*hr[kk+12] + x3.y*hr[kk+13] + x3.z*hr[kk+14] + x3.w*hr[kk+15];
    }
    float p = a0 + a1 + a2 + a3;
    p += __shfl_xor(p, 1); p += __shfl_xor(p, 2);
    if (q == 0) d_out[512 + (size_t)s * NOUT + o] = p + b2[o];
  }
}

extern "C" void kernel_launch(void* const* d_in, const int* in_sizes, int n_in,
                              void* d_out, int out_size, void* d_ws, size_t ws_size,
                              hipStream_t stream) {
  (void)in_sizes; (void)n_in; (void)out_size;
  if (ws_size < OFF_WT) return;

  // ---- all-int8 W: 4096 B/edge (+128 B bf16 scale in fixed SCL region) ----
  long pe8 = (long)((ws_size - OFF_WT) / 4096);
  if (pe8 > N_EDGES) pe8 = N_EDGES;
  pe8 &= ~63L;
  const int LIM8 = (int)pe8;
  const int TE = N_EDGES - LIM8;

  const float* x         = (const float*)d_in[0];
  const float* edge_attr = (const float*)d_in[1];
  const int*   eidx      = (const int*)d_in[2];
  const int*   stem_idx  = (const int*)d_in[4];
  const float* lin0_w = (const float*)d_in[5];
  const float* lin0_b = (const float*)d_in[6];
  const float* net_w1 = (const float*)d_in[7];
  const float* net_b1 = (const float*)d_in[8];
  const float* net_w2 = (const float*)d_in[9];
  const float* net_b2 = (const float*)d_in[10];
  const float* conv_root = (const float*)d_in[11];
  const float* conv_bias = (const float*)d_in[12];
  const float* gru_w_ih = (const float*)d_in[13];
  const float* gru_w_hh = (const float*)d_in[14];
  const float* gru_b_ih = (const float*)d_in[15];
  const float* gru_b_hh = (const float*)d_in[16];
  const float* lin1_w = (const float*)d_in[17];
  const float* lin1_b = (const float*)d_in[18];
  const float* lin2_w = (const float*)d_in[19];
  const float* lin2_b = (const float*)d_in[20];
  const float* s2s_w_ih = (const float*)d_in[21];
  const float* s2s_w_hh = (const float*)d_in[22];
  const float* s2s_b_ih = (const float*)d_in[23];
  const float* s2s_b_hh = (const float*)d_in[24];
  const float* lin3_w = (const float*)d_in[25];
  const float* lin3_b = (const float*)d_in[26];

  char* ws = (char*)d_ws;
  unsigned short* hid_p = (unsigned short*)(ws + OFF_HIDP);
  unsigned short* T2t  = (unsigned short*)(ws + OFF_T2T);
  float*          b2t  = (float*)(ws + OFF_B2T);
  float*          state= (float*)(ws + OFF_STATE);
  float*          agg  = (float*)(ws + OFF_AGG);
  float*          ideg = (float*)(ws + OFF_IDEG);
  int*            cnt  = (int*)(ws + OFF_CNT);
  int*            rp   = (int*)(ws + OFF_RP);
  int*            cur  = (int*)(ws + OFF_CUR);
  int*            src_p= (int*)(ws + OFF_SRCP);
  int*            dst_p= (int*)(ws + OFF_DSTP);
  int*            epos = (int*)(ws + OFF_EPOS);
  unsigned short* BW1  = (unsigned short*)(ws + OFF_BW1);
  unsigned short* BW2  = (unsigned short*)(ws + OFF_BW2);
  float*          wihT = (float*)(ws + OFF_WIH);
  float*          whhT = (float*)(ws + OFF_WHH);
  char*           s8   = (char*)(ws + OFF_S8);
  float*          sscale = (float*)(ws + OFF_SSC);
  unsigned short* SCLh = (unsigned short*)(ws + OFF_SCL);
  unsigned char*  W8   = (unsigned char*)(ws + OFF_WT);
  float* out = (float*)d_out;

  const int* src = eidx;
  const int* dst = eidx + N_EDGES;

  hipMemsetAsync(cnt, 0, SZ_CNT, stream);
  k_deg<<<N_EDGES / 256, 256, 0, stream>>>(dst, cnt);
  k_scan<<<1, 1024, 0, stream>>>(cnt, rp, cur, ideg);
  k_permute<<<N_EDGES / 256, 256, 0, stream>>>(src, dst, cur, src_p, dst_p, epos);
  k_prep_t2<<<(WCOLS * NHID) / 256, 256, 0, stream>>>(net_w2, net_b2, T2t, b2t);
  k_prep_gru<<<112, 256, 0, stream>>>(conv_root, gru_w_hh, gru_w_ih, BW1, BW2);
  k_prep_s2s<<<192, 256, 0, stream>>>(s2s_w_ih, s2s_w_hh, wihT, whhT);
  k_lin0<<<(N_NODES * DIM) / 256, 256, 0, stream>>>(x, lin0_w, lin0_b, state);
  k_qstate<<<N_NODES / 4, 256, 0, stream>>>(state, s8, sscale);
  k_hidden<<<(N_EDGES * NHID) / 256, 256, 0, stream>>>(edge_attr, net_w1, net_b1,
                                                       epos, hid_p);
  if (LIM8 > 0)
    k_wgemm8<<<dim3(8, LIM8 / 64), 256, 0, stream>>>(hid_p, T2t, b2t, W8, SCLh);

  for (int s = 0; s < 12; ++s) {
    k_msg_csr<<<N_NODES / 4, 256, 0, stream>>>(W8, SCLh, s8, sscale, LIM8,
                                               rp, src_p, ideg, agg);
    if (TE > 0)
      k_wmsg<<<(TE + 63) / 64, 256, 0, stream>>>(hid_p + (size_t)LIM8 * NHID, T2t, b2t,
                                                 state, src_p, dst_p, ideg, LIM8, agg);
    k_gru<<<N_NODES / 128, 512, 0, stream>>>(agg, state, BW1, BW2, conv_bias,
                                             gru_b_ih, gru_b_hh, s8, sscale);
  }

  k_s2s<<<NGRAPH, 256, 0, stream>>>(state, wihT, whhT, s2s_b_ih, s2s_b_hh,
                                    lin3_w, lin3_b, out);
  k_stem<<<NSTEM, 512, 0, stream>>>(state, stem_idx, lin1_w, lin1_b,
                                    lin2_w, lin2_b, out);
}

// Round 15
// 1956.765 us; speedup vs baseline: 1.0887x; 1.0328x over previous
//
#include <hip/hip_runtime.h>
#include <hip/hip_bf16.h>

#define N_NODES   32768
#define N_EDGES   65536
#define NGRAPH    512
#define DIM       64
#define NFEAT     14
#define NHID      128
#define WCOLS     4096
#define NSTEM     1024
#define NOUT      105

typedef __attribute__((ext_vector_type(8))) short short8;
typedef __attribute__((ext_vector_type(4))) float f32x4;

__device__ __forceinline__ float bf2f(unsigned int u16) {
  union { unsigned int i; float f; } c; c.i = u16 << 16; return c.f;
}
__device__ __forceinline__ unsigned short f2bf(float f) {
  union { float f; unsigned int i; } c; c.f = f;
  return (unsigned short)((c.i + 0x7fffu + ((c.i >> 16) & 1u)) >> 16);
}
__device__ __forceinline__ float leaky(float x) { return x > 0.f ? x : 0.01f * x; }
__device__ __forceinline__ float sigm(float x) { return 1.f / (1.f + expf(-x)); }

constexpr size_t ALN(size_t x) { return (x + 255) & ~(size_t)255; }

// ---------------- fixed workspace layout (~47 MB) ----------------
constexpr size_t OFF_HIDP = 0;
constexpr size_t SZ_HIDP  = (size_t)N_EDGES * NHID * 2;       // 16 MB bf16 (CSR order)
constexpr size_t OFF_T2T  = ALN(OFF_HIDP + SZ_HIDP);
constexpr size_t SZ_T2T   = (size_t)WCOLS * NHID * 2;         // 1 MB
constexpr size_t OFF_B2T  = ALN(OFF_T2T + SZ_T2T);
constexpr size_t SZ_B2T   = (size_t)WCOLS * 4;
constexpr size_t OFF_STATE= ALN(OFF_B2T + SZ_B2T);
constexpr size_t SZ_STATE = (size_t)N_NODES * DIM * 4;        // 8 MB
constexpr size_t OFF_AGG  = ALN(OFF_STATE + SZ_STATE);
constexpr size_t SZ_AGG   = SZ_STATE;                         // 8 MB
constexpr size_t OFF_IDEG = ALN(OFF_AGG + SZ_AGG);
constexpr size_t SZ_IDEG  = (size_t)N_NODES * 4;
constexpr size_t OFF_CNT  = ALN(OFF_IDEG + SZ_IDEG);
constexpr size_t SZ_CNT   = (size_t)N_NODES * 4;
constexpr size_t OFF_RP   = ALN(OFF_CNT + SZ_CNT);
constexpr size_t SZ_RP    = (size_t)(N_NODES + 1) * 4;
constexpr size_t OFF_CUR  = ALN(OFF_RP + SZ_RP);
constexpr size_t SZ_CUR   = (size_t)N_NODES * 4;
constexpr size_t OFF_SRCP = ALN(OFF_CUR + SZ_CUR);
constexpr size_t SZ_SRCP  = (size_t)N_EDGES * 4;
constexpr size_t OFF_DSTP = ALN(OFF_SRCP + SZ_SRCP);
constexpr size_t SZ_DSTP  = (size_t)N_EDGES * 4;
constexpr size_t OFF_EPOS = ALN(OFF_DSTP + SZ_DSTP);
constexpr size_t SZ_EPOS  = (size_t)N_EDGES * 4;
constexpr size_t OFF_BW1  = ALN(OFF_EPOS + SZ_EPOS);
constexpr size_t SZ_BW1   = 256 * 64 * 2;                  // [n=256][k=64] bf16 : root|w_hh
constexpr size_t OFF_BW2  = ALN(OFF_BW1 + SZ_BW1);
constexpr size_t SZ_BW2   = 192 * 64 * 2;                  // [n=192][k=64] bf16 : w_ih
constexpr size_t OFF_WIH  = ALN(OFF_BW2 + SZ_BW2);
constexpr size_t SZ_WIH   = 128 * 256 * 4;
constexpr size_t OFF_WHH  = ALN(OFF_WIH + SZ_WIH);
constexpr size_t SZ_WHH   = 64 * 256 * 4;
constexpr size_t OFF_S8   = ALN(OFF_WHH + SZ_WHH);
constexpr size_t SZ_S8    = (size_t)N_NODES * 64;             // 2 MB int8 state
constexpr size_t OFF_SSC  = ALN(OFF_S8 + SZ_S8);
constexpr size_t SZ_SSC   = (size_t)N_NODES * 4;
constexpr size_t OFF_SCL  = ALN(OFF_SSC + SZ_SSC);
constexpr size_t SZ_SCL   = (size_t)N_EDGES * 64 * 2;         // 8 MB bf16 scales
constexpr size_t OFF_WT   = ALN(OFF_SCL + SZ_SCL);            // W8 base

// ---------------- prep kernels ----------------
__global__ void k_deg(const int* __restrict__ dst, int* __restrict__ cnt) {
  int e = blockIdx.x * 256 + threadIdx.x;
  atomicAdd(&cnt[dst[e]], 1);
}
__global__ __launch_bounds__(1024) void k_scan(const int* __restrict__ cnt,
                                               int* __restrict__ rp,
                                               int* __restrict__ cur,
                                               float* __restrict__ ideg) {
  __shared__ int part[1024];
  const int t = threadIdx.x, base = t * 32;
  int s = 0;
  for (int i = 0; i < 32; ++i) s += cnt[base + i];
  part[t] = s;
  __syncthreads();
  for (int off = 1; off < 1024; off <<= 1) {
    int v = (t >= off) ? part[t - off] : 0;
    __syncthreads();
    part[t] += v;
    __syncthreads();
  }
  int run = part[t] - s;
  for (int i = 0; i < 32; ++i) {
    int c = cnt[base + i];
    rp[base + i] = run; cur[base + i] = run;
    ideg[base + i] = 1.0f / fmaxf((float)c, 1.0f);
    run += c;
  }
  if (t == 1023) rp[N_NODES] = run;
}
__global__ void k_permute(const int* __restrict__ src, const int* __restrict__ dst,
                          int* __restrict__ cur, int* __restrict__ src_p,
                          int* __restrict__ dst_p, int* __restrict__ epos) {
  int e = blockIdx.x * 256 + threadIdx.x;
  int d = dst[e];
  int p = atomicAdd(&cur[d], 1);
  src_p[p] = src[e]; dst_p[p] = d; epos[e] = p;
}
// T2t[r=o*64+i][h] = net_w2[(i*64+o)][h]; b2t[r] = net_b2[i*64+o]
__global__ void k_prep_t2(const float* __restrict__ w2, const float* __restrict__ b2,
                          unsigned short* __restrict__ T2t, float* __restrict__ b2t) {
  int gid = blockIdx.x * 256 + threadIdx.x;
  int r = gid >> 7, h = gid & 127;
  int srow = (r & 63) * 64 + (r >> 6);
  T2t[gid] = f2bf(w2[(size_t)srow * 128 + h]);
  if (h == 0) b2t[r] = b2[srow];
}
__global__ void k_prep_gru(const float* __restrict__ root, const float* __restrict__ whh,
                           const float* __restrict__ wih,
                           unsigned short* __restrict__ BW1, unsigned short* __restrict__ BW2) {
  int gid = blockIdx.x * 256 + threadIdx.x;
  if (gid >= 64 * 448) return;
  int i = gid / 448, c = gid % 448;
  if (c < 64)        BW1[c * 64 + i] = f2bf(root[i * 64 + c]);
  else if (c < 256)  BW1[c * 64 + i] = f2bf(whh[(c - 64) * 64 + i]);
  else               BW2[(c - 256) * 64 + i] = f2bf(wih[(c - 256) * 64 + i]);
}
__global__ void k_prep_s2s(const float* __restrict__ wih, const float* __restrict__ whh,
                           float* __restrict__ wihT, float* __restrict__ whhT) {
  int gid = blockIdx.x * 256 + threadIdx.x;
  if (gid < 32768) { int j = gid >> 8, k = gid & 255; wihT[gid] = wih[k * 128 + j]; }
  else { int g2 = gid - 32768; int j = g2 >> 8, k = g2 & 255; whhT[g2] = whh[k * 64 + j]; }
}
__global__ void k_lin0(const float* __restrict__ x, const float* __restrict__ w,
                       const float* __restrict__ b, float* __restrict__ state) {
  int gid = blockIdx.x * 256 + threadIdx.x;
  int n = gid >> 6, o = gid & 63;
  float acc = b[o];
  #pragma unroll
  for (int f = 0; f < NFEAT; ++f) acc += x[(size_t)n * NFEAT + f] * w[o * NFEAT + f];
  state[gid] = leaky(acc);
}
__global__ void k_hidden(const float* __restrict__ ea, const float* __restrict__ w1,
                         const float* __restrict__ b1, const int* __restrict__ epos,
                         unsigned short* __restrict__ hid_p) {
  int gid = blockIdx.x * 256 + threadIdx.x;
  int e = gid >> 7, h = gid & 127;
  float acc = b1[h];
  #pragma unroll
  for (int d = 0; d < 4; ++d) acc += ea[(size_t)e * 4 + d] * w1[h * 4 + d];
  hid_p[(size_t)epos[e] * 128 + h] = f2bf(leaky(acc));
}
// quantize state rows to int8 (wave per node)
__global__ __launch_bounds__(256) void k_qstate(const float* __restrict__ state,
                                                char* __restrict__ s8,
                                                float* __restrict__ sscale) {
  __shared__ char q8[4][64];
  __shared__ float scs[4];
  const int t = threadIdx.x, wv = t >> 6, ln = t & 63;
  const int n = blockIdx.x * 4 + wv;
  float v = state[(size_t)n * 64 + ln];
  float m = fabsf(v);
  #pragma unroll
  for (int off = 1; off < 64; off <<= 1) m = fmaxf(m, __shfl_xor(m, off));
  float inv = m > 0.f ? 127.f / m : 0.f;
  q8[wv][ln] = (char)(int)rintf(v * inv);
  if (ln == 0) scs[wv] = m * (1.f / 127.f);
  __syncthreads();
  if (t < 64) {
    int w2 = t >> 4, c = t & 15;
    reinterpret_cast<int*>(s8)[((size_t)(blockIdx.x * 4 + w2)) * 16 + c] =
        reinterpret_cast<const int*>(q8[w2])[c];
  }
  if (t < 4) sscale[blockIdx.x * 4 + t] = scs[t];
}

// ---------------- W build GEMM: int8 output, chunk-coalesced layout (r9 + bf16 scale) ----
// W8[e*4096 + (i>>4)*1024 + o*16 + (i&15)] ; SCLh[e*64 + o] (bf16)
#define WG_PAD 136
__global__ __launch_bounds__(256) void k_wgemm(const unsigned short* __restrict__ A,
                                               const unsigned short* __restrict__ Bt,
                                               const float* __restrict__ b2t,
                                               unsigned char* __restrict__ W8,
                                               unsigned short* __restrict__ SCLh) {
  __shared__ __align__(16) unsigned short As[64 * WG_PAD];
  __shared__ __align__(16) unsigned short Bs[64 * WG_PAD];
  __shared__ __align__(16) char pk[64][64];
  const int nb = blockIdx.x, mb = blockIdx.y, t = threadIdx.x;
  #pragma unroll
  for (int j = 0; j < 4; ++j) {
    int c = t + 256 * j;
    int row = c >> 4, col8 = (c & 15) * 8;
    *reinterpret_cast<uint4*>(&As[row * WG_PAD + col8]) =
        *reinterpret_cast<const uint4*>(A + (size_t)(mb * 64 + row) * 128 + col8);
    *reinterpret_cast<uint4*>(&Bs[row * WG_PAD + col8]) =
        *reinterpret_cast<const uint4*>(Bt + (size_t)(nb * 64 + row) * 128 + col8);
  }
  __syncthreads();
  const int wv = t >> 6, ln = t & 63, r = ln & 15, g = ln >> 4;
  f32x4 acc[4] = {};
  #pragma unroll
  for (int ks = 0; ks < 4; ++ks) {
    int kk = ks * 32 + g * 8;
    short8 a = *reinterpret_cast<const short8*>(&As[(wv * 16 + r) * WG_PAD + kk]);
    #pragma unroll
    for (int nt = 0; nt < 4; ++nt) {
      short8 b = *reinterpret_cast<const short8*>(&Bs[(nt * 16 + r) * WG_PAD + kk]);
      acc[nt] = __builtin_amdgcn_mfma_f32_16x16x32_bf16(a, b, acc[nt], 0, 0, 0);
    }
  }
  float bias[4];
  #pragma unroll
  for (int nt = 0; nt < 4; ++nt) bias[nt] = b2t[nb * 64 + nt * 16 + r];
  #pragma unroll
  for (int j = 0; j < 4; ++j) {
    int e_l = wv * 16 + g * 4 + j;
    float w[4], m = 0.f;
    #pragma unroll
    for (int nt = 0; nt < 4; ++nt) { w[nt] = acc[nt][j] + bias[nt]; m = fmaxf(m, fabsf(w[nt])); }
    m = fmaxf(m, __shfl_xor(m, 1)); m = fmaxf(m, __shfl_xor(m, 2));
    m = fmaxf(m, __shfl_xor(m, 4)); m = fmaxf(m, __shfl_xor(m, 8));
    float inv = m > 0.f ? 127.f / m : 0.f;
    #pragma unroll
    for (int nt = 0; nt < 4; ++nt)
      pk[e_l][nt * 16 + r] = (char)(int)rintf(w[nt] * inv);
    if (r == 0) {
      size_t e8 = (size_t)mb * 64 + e_l;
      SCLh[e8 * 64 + nb] = f2bf(m * (1.f / 127.f));
    }
  }
  __syncthreads();
  {
    int e_l = t >> 2, jc = t & 3;
    size_t e8 = (size_t)mb * 64 + e_l;
    *reinterpret_cast<uint4*>(W8 + e8 * 4096 + jc * 1024 + nb * 16) =
        *reinterpret_cast<const uint4*>(&pk[e_l][jc * 16]);
  }
}

// ---------------- per-step msg: CSR gather, int8 x int8 via sdot4, bf16 scales ----------
__device__ __forceinline__ int dot64(const uint4* __restrict__ wp, const int* __restrict__ s) {
  int u = 0;
  #pragma unroll
  for (int j = 0; j < 4; ++j) {
    uint4 v = wp[j * 64];                       // +j*1024 bytes
    u = __builtin_amdgcn_sdot4((int)v.x, s[j * 4 + 0], u, false);
    u = __builtin_amdgcn_sdot4((int)v.y, s[j * 4 + 1], u, false);
    u = __builtin_amdgcn_sdot4((int)v.z, s[j * 4 + 2], u, false);
    u = __builtin_amdgcn_sdot4((int)v.w, s[j * 4 + 3], u, false);
  }
  return u;
}

__global__ __launch_bounds__(256) void k_msg_csr(const unsigned char* __restrict__ W8,
                                                 const unsigned short* __restrict__ SCLh,
                                                 const char* __restrict__ s8,
                                                 const float* __restrict__ sscale,
                                                 int lim8,
                                                 const int* __restrict__ rp,
                                                 const int* __restrict__ src_p,
                                                 const float* __restrict__ ideg,
                                                 float* __restrict__ agg) {
  const int wv = threadIdx.x >> 6, ln = threadIdx.x & 63;
  const int d = blockIdx.x * 4 + wv;
  int k0 = rp[d], k1 = rp[d + 1];
  if (k1 > lim8) k1 = lim8;            // tail edges handled by k_wmsg
  float acc = 0.f;
  int k = k0;
  for (; k + 2 <= k1; k += 2) {
    const uint4* wA = reinterpret_cast<const uint4*>(W8 + (size_t)k * 4096 + ln * 16);
    const uint4* wB = reinterpret_cast<const uint4*>(W8 + (size_t)(k + 1) * 4096 + ln * 16);
    int sA = __builtin_amdgcn_readfirstlane(src_p[k]);
    int sB = __builtin_amdgcn_readfirstlane(src_p[k + 1]);
    const int* rA = reinterpret_cast<const int*>(s8 + (size_t)sA * 64);
    const int* rB = reinterpret_cast<const int*>(s8 + (size_t)sB * 64);
    float fA = bf2f(SCLh[(size_t)k * 64 + ln]) * sscale[sA];
    float fB = bf2f(SCLh[(size_t)k * 64 + 64 + ln]) * sscale[sB];
    int uA = dot64(wA, rA);
    int uB = dot64(wB, rB);
    acc = fmaf((float)uA, fA, acc);
    acc = fmaf((float)uB, fB, acc);
  }
  if (k < k1) {
    const uint4* wA = reinterpret_cast<const uint4*>(W8 + (size_t)k * 4096 + ln * 16);
    int sA = __builtin_amdgcn_readfirstlane(src_p[k]);
    const int* rA = reinterpret_cast<const int*>(s8 + (size_t)sA * 64);
    float fA = bf2f(SCLh[(size_t)k * 64 + ln]) * sscale[sA];
    acc = fmaf((float)dot64(wA, rA), fA, acc);
  }
  agg[(size_t)d * 64 + ln] = acc * ideg[d];
}

// ---------------- fallback transient (only if ws too small): adds on top ----------------
#define WM_PAD 136
__global__ __launch_bounds__(256) void k_wmsg(const unsigned short* __restrict__ hid,
                                              const unsigned short* __restrict__ T2t,
                                              const float* __restrict__ b2t,
                                              const float* __restrict__ state,
                                              const int* __restrict__ srcs,
                                              const int* __restrict__ dsts,
                                              const float* __restrict__ ideg,
                                              int e0,
                                              float* __restrict__ agg) {
  __shared__ __align__(16) unsigned short As[64 * WM_PAD];
  __shared__ __align__(16) unsigned short Bs[2][64 * WM_PAD];
  __shared__ __align__(16) float Ss[64][68];
  __shared__ int dstl[64]; __shared__ float idgl[64];
  __shared__ int srcl[64];
  const int t = threadIdx.x;
  const int eb = blockIdx.x * 64;
  if (t < 64) {
    int e = e0 + eb + t;
    srcl[t] = srcs[e];
    int d = dsts[e]; dstl[t] = d; idgl[t] = ideg[d];
  }
  __syncthreads();
  #pragma unroll
  for (int j = 0; j < 4; ++j) {
    int c = t + 256 * j;
    int row = c >> 4, col8 = (c & 15) * 8;
    *reinterpret_cast<uint4*>(&As[row * WM_PAD + col8]) =
        *reinterpret_cast<const uint4*>(hid + (size_t)(eb + row) * 128 + col8);
  }
  #pragma unroll
  for (int j = 0; j < 4; ++j) {
    int c = t + 256 * j;
    int row = c >> 4, q = (c & 15) * 4;
    *reinterpret_cast<float4*>(&Ss[row][q]) =
        *reinterpret_cast<const float4*>(state + (size_t)srcl[row] * 64 + q);
  }
  #pragma unroll
  for (int j = 0; j < 4; ++j) {
    int c = t + 256 * j;
    int row = c >> 4, col8 = (c & 15) * 8;
    *reinterpret_cast<uint4*>(&Bs[0][row * WM_PAD + col8]) =
        *reinterpret_cast<const uint4*>(T2t + (size_t)row * 128 + col8);
  }
  __syncthreads();
  const int wv = t >> 6, ln = t & 63, r = ln & 15, g = ln >> 4;
  for (int nb = 0; nb < 64; ++nb) {
    const int cur = nb & 1;
    if (nb + 1 < 64) {
      #pragma unroll
      for (int j = 0; j < 4; ++j) {
        int c = t + 256 * j;
        int row = c >> 4, col8 = (c & 15) * 8;
        *reinterpret_cast<uint4*>(&Bs[cur ^ 1][row * WM_PAD + col8]) =
            *reinterpret_cast<const uint4*>(T2t + (size_t)((nb + 1) * 64 + row) * 128 + col8);
      }
    }
    f32x4 acc[4] = {};
    #pragma unroll
    for (int ks = 0; ks < 4; ++ks) {
      int kk = ks * 32 + g * 8;
      short8 a = *reinterpret_cast<const short8*>(&As[(wv * 16 + r) * WM_PAD + kk]);
      #pragma unroll
      for (int nt = 0; nt < 4; ++nt) {
        short8 b = *reinterpret_cast<const short8*>(&Bs[cur][(nt * 16 + r) * WM_PAD + kk]);
        acc[nt] = __builtin_amdgcn_mfma_f32_16x16x32_bf16(a, b, acc[nt], 0, 0, 0);
      }
    }
    float bias[4];
    #pragma unroll
    for (int nt = 0; nt < 4; ++nt) bias[nt] = b2t[nb * 64 + nt * 16 + r];
    float pj[4];
    #pragma unroll
    for (int j = 0; j < 4; ++j) {
      int row = wv * 16 + g * 4 + j;
      float p = 0.f;
      #pragma unroll
      for (int nt = 0; nt < 4; ++nt)
        p += (acc[nt][j] + bias[nt]) * Ss[row][nt * 16 + r];
      pj[j] = p;
    }
    #pragma unroll
    for (int j = 0; j < 4; ++j) {
      float p = pj[j];
      p += __shfl_xor(p, 1); p += __shfl_xor(p, 2);
      p += __shfl_xor(p, 4); p += __shfl_xor(p, 8);
      pj[j] = p;
    }
    if (r == 0) {
      #pragma unroll
      for (int j = 0; j < 4; ++j) {
        int row = wv * 16 + g * 4 + j;
        atomicAdd(&agg[(size_t)dstl[row] * 64 + nb], pj[j] * idgl[row]);
      }
    }
    __syncthreads();
  }
}

// ---------------- per-step fused: root GEMM + m + GRU gates + state re-quant (r9) --------
#define KPAD 72
__global__ __launch_bounds__(512, 1) void k_gru(const float* __restrict__ agg,
                                                float* __restrict__ state,
                                                const unsigned short* __restrict__ BW1,
                                                const unsigned short* __restrict__ BW2,
                                                const float* __restrict__ conv_bias,
                                                const float* __restrict__ b_ih,
                                                const float* __restrict__ b_hh,
                                                char* __restrict__ s8,
                                                float* __restrict__ sscale) {
  __shared__ __align__(16) unsigned short As[128 * KPAD];
  __shared__ __align__(16) unsigned short Ms[128 * KPAD];
  __shared__ __align__(16) unsigned short B1s[256 * KPAD];
  __shared__ __align__(16) unsigned short B2s[192 * KPAD];
  const int t = threadIdx.x;
  const int rowbase = blockIdx.x * 128;
  #pragma unroll
  for (int j = 0; j < 2; ++j) {
    int c = t + 512 * j;
    int row = c >> 3, col8 = (c & 7) * 8;
    const float* sp = state + (size_t)(rowbase + row) * 64 + col8;
    float4 f0 = *reinterpret_cast<const float4*>(sp);
    float4 f1 = *reinterpret_cast<const float4*>(sp + 4);
    short8 hv;
    hv[0] = (short)f2bf(f0.x); hv[1] = (short)f2bf(f0.y);
    hv[2] = (short)f2bf(f0.z); hv[3] = (short)f2bf(f0.w);
    hv[4] = (short)f2bf(f1.x); hv[5] = (short)f2bf(f1.y);
    hv[6] = (short)f2bf(f1.z); hv[7] = (short)f2bf(f1.w);
    *reinterpret_cast<short8*>(&As[row * KPAD + col8]) = hv;
  }
  #pragma unroll
  for (int j = 0; j < 4; ++j) {
    int c = t + 512 * j;
    int row = c >> 3, col8 = (c & 7) * 8;
    *reinterpret_cast<uint4*>(&B1s[row * KPAD + col8]) =
        *reinterpret_cast<const uint4*>(BW1 + row * 64 + col8);
  }
  #pragma unroll
  for (int j = 0; j < 3; ++j) {
    int c = t + 512 * j;
    int row = c >> 3, col8 = (c & 7) * 8;
    *reinterpret_cast<uint4*>(&B2s[row * KPAD + col8]) =
        *reinterpret_cast<const uint4*>(BW2 + row * 64 + col8);
  }
  __syncthreads();
  const int wv = t >> 6, ln = t & 63, r = ln & 15, g = ln >> 4;
  f32x4 acc1[16] = {};
  #pragma unroll
  for (int ks = 0; ks < 2; ++ks) {
    int kk = ks * 32 + g * 8;
    short8 a = *reinterpret_cast<const short8*>(&As[(wv * 16 + r) * KPAD + kk]);
    #pragma unroll
    for (int nt = 0; nt < 16; ++nt) {
      short8 b = *reinterpret_cast<const short8*>(&B1s[(nt * 16 + r) * KPAD + kk]);
      acc1[nt] = __builtin_amdgcn_mfma_f32_16x16x32_bf16(a, b, acc1[nt], 0, 0, 0);
    }
  }
  #pragma unroll
  for (int nt = 0; nt < 4; ++nt) {
    int col = nt * 16 + r;
    float cb = conv_bias[col];
    #pragma unroll
    for (int j = 0; j < 4; ++j) {
      int lrow = wv * 16 + g * 4 + j;
      float mv = agg[(size_t)(rowbase + lrow) * 64 + col] + acc1[nt][j] + cb;
      Ms[lrow * KPAD + col] = f2bf(leaky(mv));
    }
  }
  __syncthreads();
  f32x4 acc2[12] = {};
  #pragma unroll
  for (int ks = 0; ks < 2; ++ks) {
    int kk = ks * 32 + g * 8;
    short8 a = *reinterpret_cast<const short8*>(&Ms[(wv * 16 + r) * KPAD + kk]);
    #pragma unroll
    for (int nt = 0; nt < 12; ++nt) {
      short8 b = *reinterpret_cast<const short8*>(&B2s[(nt * 16 + r) * KPAD + kk]);
      acc2[nt] = __builtin_amdgcn_mfma_f32_16x16x32_bf16(a, b, acc2[nt], 0, 0, 0);
    }
  }
  float hnew[4][4];
  #pragma unroll
  for (int nt = 0; nt < 4; ++nt) {
    int o = nt * 16 + r;
    float bir = b_ih[o],       bhr = b_hh[o];
    float biz = b_ih[64 + o],  bhz = b_hh[64 + o];
    float bin = b_ih[128 + o], bhn = b_hh[128 + o];
    #pragma unroll
    for (int j = 0; j < 4; ++j) {
      size_t gidx = (size_t)(rowbase + wv * 16 + g * 4 + j) * 64 + o;
      float rr = sigm(acc2[nt][j] + bir + acc1[4 + nt][j] + bhr);
      float zz = sigm(acc2[4 + nt][j] + biz + acc1[8 + nt][j] + bhz);
      float nn = tanhf(acc2[8 + nt][j] + bin + rr * (acc1[12 + nt][j] + bhn));
      float hold = state[gidx];
      float hv = (1.f - zz) * nn + zz * hold;
      state[gidx] = hv;
      hnew[nt][j] = hv;
    }
  }
  // re-quantize new state rows to int8 (As LDS reused as byte tile)
  char* s8t = (char*)As;
  #pragma unroll
  for (int j = 0; j < 4; ++j) {
    float mx = 0.f;
    #pragma unroll
    for (int nt = 0; nt < 4; ++nt) mx = fmaxf(mx, fabsf(hnew[nt][j]));
    mx = fmaxf(mx, __shfl_xor(mx, 1)); mx = fmaxf(mx, __shfl_xor(mx, 2));
    mx = fmaxf(mx, __shfl_xor(mx, 4)); mx = fmaxf(mx, __shfl_xor(mx, 8));
    float inv = mx > 0.f ? 127.f / mx : 0.f;
    int lrow = wv * 16 + g * 4 + j;
    #pragma unroll
    for (int nt = 0; nt < 4; ++nt)
      s8t[lrow * 64 + nt * 16 + r] = (char)(int)rintf(hnew[nt][j] * inv);
    if (r == 0) sscale[rowbase + lrow] = mx * (1.f / 127.f);
  }
  __syncthreads();
  {
    int row = t >> 2, c = t & 3;
    *reinterpret_cast<uint4*>(s8 + ((size_t)(rowbase + row)) * 64 + c * 16) =
        *reinterpret_cast<const uint4*>(s8t + row * 64 + c * 16);
  }
}

// ---------------- Set2Set ----------------
__global__ __launch_bounds__(256) void k_s2s(const float* __restrict__ state,
                                             const float* __restrict__ wihT,
                                             const float* __restrict__ whhT,
                                             const float* __restrict__ b_ih,
                                             const float* __restrict__ b_hh,
                                             const float* __restrict__ lin3_w,
                                             const float* __restrict__ lin3_b,
                                             float* __restrict__ d_out) {
  __shared__ float tile[64 * 65];
  __shared__ float qs[128], hhs[64], ccs[64], gates[256], attw[64];
  const int g = blockIdx.x, t = threadIdx.x;
  for (int c = t; c < 64 * 64; c += 256) {
    int row = c >> 6, col = c & 63;
    tile[row * 65 + col] = state[(size_t)(g * 64 + row) * 64 + col];
  }
  if (t < 128) qs[t] = 0.f;
  if (t < 64) { hhs[t] = 0.f; ccs[t] = 0.f; }
  __syncthreads();
  for (int it = 0; it < 3; ++it) {
    float acc = b_ih[t] + b_hh[t];
    for (int j = 0; j < 128; ++j) acc += qs[j] * wihT[j * 256 + t];
    for (int j = 0; j < 64; ++j)  acc += hhs[j] * whhT[j * 256 + t];
    gates[t] = acc;
    __syncthreads();
    if (t < 64) {
      float ci = sigm(gates[t]), cf = sigm(gates[64 + t]);
      float cg = tanhf(gates[128 + t]), co = sigm(gates[192 + t]);
      float c2 = cf * ccs[t] + ci * cg;
      ccs[t] = c2;
      float h2 = co * tanhf(c2);
      hhs[t] = h2; qs[t] = h2;
    }
    __syncthreads();
    if (t < 64) {
      float e = 0.f;
      for (int o = 0; o < 64; ++o) e += tile[t * 65 + o] * qs[o];
      float m = e;
      for (int off = 32; off; off >>= 1) m = fmaxf(m, __shfl_xor(m, off));
      float ex = expf(e - m);
      float s = ex;
      for (int off = 32; off; off >>= 1) s += __shfl_xor(s, off);
      attw[t] = ex / s;
    }
    __syncthreads();
    if (t < 64) {
      float racc = 0.f;
      for (int j = 0; j < 64; ++j) racc += attw[j] * tile[j * 65 + t];
      qs[64 + t] = racc;
    }
    __syncthreads();
  }
  if (t < 64) {
    float v = qs[t] * lin3_w[t] + qs[64 + t] * lin3_w[64 + t];
    for (int off = 32; off; off >>= 1) v += __shfl_xor(v, off);
    if (t == 0) d_out[g] = v + lin3_b[0];
  }
}

// ---------------- per-stem head ----------------
__global__ __launch_bounds__(512) void k_stem(const float* __restrict__ state,
                                              const int* __restrict__ stem_idx,
                                              const float* __restrict__ w1,
                                              const float* __restrict__ b1,
                                              const float* __restrict__ w2,
                                              const float* __restrict__ b2,
                                              float* __restrict__ d_out) {
  __shared__ float feat[64];
  __shared__ float hidl[512];
  const int t = threadIdx.x, s = blockIdx.x;
  if (t < 64) feat[t] = state[(size_t)stem_idx[s] * 64 + t];
  __syncthreads();
  {
    const float* wr = w1 + (size_t)t * 64;
    float a0 = 0.f, a1 = 0.f, a2 = 0.f, a3 = 0.f;
    #pragma unroll
    for (int i = 0; i < 64; i += 16) {
      float4 x0 = *reinterpret_cast<const float4*>(wr + i);
      float4 x1 = *reinterpret_cast<const float4*>(wr + i + 4);
      float4 x2 = *reinterpret_cast<const float4*>(wr + i + 8);
      float4 x3 = *reinterpret_cast<const float4*>(wr + i + 12);
      a0 += x0.x*feat[i]    + x0.y*feat[i+1]  + x0.z*feat[i+2]  + x0.w*feat[i+3];
      a1 += x1.x*feat[i+4]  + x1.y*feat[i+5]  + x1.z*feat[i+6]  + x1.w*feat[i+7];
      a2 += x2.x*feat[i+8]  + x2.y*feat[i+9]  + x2.z*feat[i+10] + x2.w*feat[i+11];
      a3 += x3.x*feat[i+12] + x3.y*feat[i+13] + x3.z*feat[i+14] + x3.w*feat[i+15];
    }
    hidl[t] = leaky(a0 + a1 + a2 + a3 + b1[t]);
  }
  __syncthreads();
  if (t < 4 * NOUT) {
    int o = t >> 2, q = t & 3;
    const float* wr = w2 + (size_t)o * 512 + q * 128;
    const float* hr = hidl + q * 128;
    float a0 = 0.f, a1 = 0.f, a2 = 0.f, a3 = 0.f;
    #pragma unroll
    for (int kk = 0; kk < 128; kk += 16) {
      float4 x0 = *reinterpret_cast<const float4*>(wr + kk);
      float4 x1 = *reinterpret_cast<const float4*>(wr + kk + 4);
      float4 x2 = *reinterpret_cast<const float4*>(wr + kk + 8);
      float4 x3 = *reinterpret_cast<const float4*>(wr + kk + 12);
      a0 += x0.x*hr[kk]    + x0.y*hr[kk+1]  + x0.z*hr[kk+2]  + x0.w*hr[kk+3];
      a1 += x1.x*hr[kk+4]  + x1.y*hr[kk+5]  + x1.z*hr[kk+6]  + x1.w*hr[kk+7];
      a2 += x2.x*hr[kk+8]  + x2.y*hr[kk+9]  + x2.z*hr[kk+10] + x2.w*hr[kk+11];
      a3 += x3.x*hr[kk+12] + x3.y*hr[kk+13] + x3.z*hr[kk+14] + x3.w*hr[kk+15];
    }
    float p = a0 + a1 + a2 + a3;
    p += __shfl_xor(p, 1); p += __shfl_xor(p, 2);
    if (q == 0) d_out[512 + (size_t)s * NOUT + o] = p + b2[o];
  }
}

extern "C" void kernel_launch(void* const* d_in, const int* in_sizes, int n_in,
                              void* d_out, int out_size, void* d_ws, size_t ws_size,
                              hipStream_t stream) {
  (void)in_sizes; (void)n_in; (void)out_size;
  if (ws_size < OFF_WT) return;

  // ---- all-int8 W: 4096 B/edge (+128 B bf16 scale in fixed SCL region) ----
  long pe8 = (long)((ws_size - OFF_WT) / 4096);
  if (pe8 > N_EDGES) pe8 = N_EDGES;
  pe8 &= ~63L;
  const int LIM8 = (int)pe8;
  const int TE = N_EDGES - LIM8;

  const float* x         = (const float*)d_in[0];
  const float* edge_attr = (const float*)d_in[1];
  const int*   eidx      = (const int*)d_in[2];
  const int*   stem_idx  = (const int*)d_in[4];
  const float* lin0_w = (const float*)d_in[5];
  const float* lin0_b = (const float*)d_in[6];
  const float* net_w1 = (const float*)d_in[7];
  const float* net_b1 = (const float*)d_in[8];
  const float* net_w2 = (const float*)d_in[9];
  const float* net_b2 = (const float*)d_in[10];
  const float* conv_root = (const float*)d_in[11];
  const float* conv_bias = (const float*)d_in[12];
  const float* gru_w_ih = (const float*)d_in[13];
  const float* gru_w_hh = (const float*)d_in[14];
  const float* gru_b_ih = (const float*)d_in[15];
  const float* gru_b_hh = (const float*)d_in[16];
  const float* lin1_w = (const float*)d_in[17];
  const float* lin1_b = (const float*)d_in[18];
  const float* lin2_w = (const float*)d_in[19];
  const float* lin2_b = (const float*)d_in[20];
  const float* s2s_w_ih = (const float*)d_in[21];
  const float* s2s_w_hh = (const float*)d_in[22];
  const float* s2s_b_ih = (const float*)d_in[23];
  const float* s2s_b_hh = (const float*)d_in[24];
  const float* lin3_w = (const float*)d_in[25];
  const float* lin3_b = (const float*)d_in[26];

  char* ws = (char*)d_ws;
  unsigned short* hid_p = (unsigned short*)(ws + OFF_HIDP);
  unsigned short* T2t  = (unsigned short*)(ws + OFF_T2T);
  float*          b2t  = (float*)(ws + OFF_B2T);
  float*          state= (float*)(ws + OFF_STATE);
  float*          agg  = (float*)(ws + OFF_AGG);
  float*          ideg = (float*)(ws + OFF_IDEG);
  int*            cnt  = (int*)(ws + OFF_CNT);
  int*            rp   = (int*)(ws + OFF_RP);
  int*            cur  = (int*)(ws + OFF_CUR);
  int*            src_p= (int*)(ws + OFF_SRCP);
  int*            dst_p= (int*)(ws + OFF_DSTP);
  int*            epos = (int*)(ws + OFF_EPOS);
  unsigned short* BW1  = (unsigned short*)(ws + OFF_BW1);
  unsigned short* BW2  = (unsigned short*)(ws + OFF_BW2);
  float*          wihT = (float*)(ws + OFF_WIH);
  float*          whhT = (float*)(ws + OFF_WHH);
  char*           s8   = (char*)(ws + OFF_S8);
  float*          sscale = (float*)(ws + OFF_SSC);
  unsigned short* SCLh = (unsigned short*)(ws + OFF_SCL);
  unsigned char*  W8   = (unsigned char*)(ws + OFF_WT);
  float* out = (float*)d_out;

  const int* src = eidx;
  const int* dst = eidx + N_EDGES;

  hipMemsetAsync(cnt, 0, SZ_CNT, stream);
  k_deg<<<N_EDGES / 256, 256, 0, stream>>>(dst, cnt);
  k_scan<<<1, 1024, 0, stream>>>(cnt, rp, cur, ideg);
  k_permute<<<N_EDGES / 256, 256, 0, stream>>>(src, dst, cur, src_p, dst_p, epos);
  k_prep_t2<<<(WCOLS * NHID) / 256, 256, 0, stream>>>(net_w2, net_b2, T2t, b2t);
  k_prep_gru<<<112, 256, 0, stream>>>(conv_root, gru_w_hh, gru_w_ih, BW1, BW2);
  k_prep_s2s<<<192, 256, 0, stream>>>(s2s_w_ih, s2s_w_hh, wihT, whhT);
  k_lin0<<<(N_NODES * DIM) / 256, 256, 0, stream>>>(x, lin0_w, lin0_b, state);
  k_qstate<<<N_NODES / 4, 256, 0, stream>>>(state, s8, sscale);
  k_hidden<<<(N_EDGES * NHID) / 256, 256, 0, stream>>>(edge_attr, net_w1, net_b1,
                                                       epos, hid_p);
  if (LIM8 > 0)
    k_wgemm<<<dim3(WCOLS / 64, LIM8 / 64), 256, 0, stream>>>(hid_p, T2t, b2t, W8, SCLh);

  for (int s = 0; s < 12; ++s) {
    k_msg_csr<<<N_NODES / 4, 256, 0, stream>>>(W8, SCLh, s8, sscale, LIM8,
                                               rp, src_p, ideg, agg);
    if (TE > 0)
      k_wmsg<<<(TE + 63) / 64, 256, 0, stream>>>(hid_p + (size_t)LIM8 * NHID, T2t, b2t,
                                                 state, src_p, dst_p, ideg, LIM8, agg);
    k_gru<<<N_NODES / 128, 512, 0, stream>>>(agg, state, BW1, BW2, conv_bias,
                                             gru_b_ih, gru_b_hh, s8, sscale);
  }

  k_s2s<<<NGRAPH, 256, 0, stream>>>(state, wihT, whhT, s2s_b_ih, s2s_b_hh,
                                    lin3_w, lin3_b, out);
  k_stem<<<NSTEM, 512, 0, stream>>>(state, stem_idx, lin1_w, lin1_b,
                                    lin2_w, lin2_b, out);
}